// Round 1
// baseline (1570.110 us; speedup 1.0000x reference)
//
#include <hip/hip_runtime.h>
#include <hip/hip_bf16.h>
#include <cstdint>

#define DIMC 192
#define NHEAD 4
#define BB 4
#define HH 128
#define WW 128
#define NN 16384
#define D3 576
#define CHD 48

// ---------- bf16 helpers (raw uint16 storage, RNE convert) ----------
__device__ __forceinline__ float bf2f(uint16_t v) {
    return __uint_as_float(((uint32_t)v) << 16);
}
__device__ __forceinline__ float2 upk2(uint32_t u) {
    float2 r;
    r.x = __uint_as_float(u << 16);
    r.y = __uint_as_float(u & 0xffff0000u);
    return r;
}
__device__ __forceinline__ uint16_t f2bf(float f) {
    uint32_t x = __float_as_uint(f);
    return (uint16_t)((x + 0x7fffu + ((x >> 16) & 1u)) >> 16);
}

// ---------- K1: conv1x1 qkv: fp32 in [B][192][NN] -> bf16 out [B][576][NN] ----------
// grid = B*256 blocks (64-px tiles), block = 256 (16 px-thr x 16 oc-thr), 4x4 reg tile
__global__ __launch_bounds__(256) void k_conv_qkv(
    const float* __restrict__ x, const float* __restrict__ w,
    const float* __restrict__ bias, uint16_t* __restrict__ out)
{
    __shared__ float xs[DIMC][64];
    const int t = threadIdx.x;
    const int blk = blockIdx.x;
    const int b = blk >> 8;
    const int n0 = (blk & 255) * 64;
    const float* xb = x + ((size_t)b * DIMC) * NN + n0;
    for (int i = t; i < DIMC * 16; i += 256) {
        int c = i >> 4, f = i & 15;
        float4 v = *reinterpret_cast<const float4*>(xb + (size_t)c * NN + f * 4);
        *reinterpret_cast<float4*>(&xs[c][f * 4]) = v;
    }
    __syncthreads();
    const int pt = t & 15, ot = t >> 4;
    uint16_t* ob = out + ((size_t)b * D3) * NN + n0 + pt * 4;
    for (int og = 0; og < 9; ++og) {
        const int oc0 = og * 64 + ot * 4;
        float acc[4][4];
#pragma unroll
        for (int i = 0; i < 4; ++i) {
            float bv = bias[oc0 + i];
#pragma unroll
            for (int j = 0; j < 4; ++j) acc[i][j] = bv;
        }
        const float* w0 = w + (size_t)oc0 * DIMC;
#pragma unroll 4
        for (int c = 0; c < DIMC; ++c) {
            float4 xv = *reinterpret_cast<const float4*>(&xs[c][pt * 4]);
#pragma unroll
            for (int i = 0; i < 4; ++i) {
                float wv = w0[i * DIMC + c];
                acc[i][0] = fmaf(wv, xv.x, acc[i][0]);
                acc[i][1] = fmaf(wv, xv.y, acc[i][1]);
                acc[i][2] = fmaf(wv, xv.z, acc[i][2]);
                acc[i][3] = fmaf(wv, xv.w, acc[i][3]);
            }
        }
#pragma unroll
        for (int i = 0; i < 4; ++i) {
            ushort4 pk;
            pk.x = f2bf(acc[i][0]); pk.y = f2bf(acc[i][1]);
            pk.z = f2bf(acc[i][2]); pk.w = f2bf(acc[i][3]);
            *reinterpret_cast<ushort4*>(ob + (size_t)(oc0 + i) * NN) = pk;
        }
    }
}

// ---------- K2: depthwise 3x3 + bias, bf16 in -> bf16 out ----------
// block (128,2), grid (1, 64, B*576)
__global__ __launch_bounds__(256) void k_dwconv(
    const uint16_t* __restrict__ in, const float* __restrict__ w9,
    const float* __restrict__ bias, uint16_t* __restrict__ out)
{
    const int x = threadIdx.x;
    const int y = blockIdx.y * 2 + threadIdx.y;
    const int bc = blockIdx.z;
    const int ch = bc % D3;
    const uint16_t* p = in + (size_t)bc * NN;
    float wv[9];
#pragma unroll
    for (int k = 0; k < 9; ++k) wv[k] = w9[ch * 9 + k];
    float acc = bias[ch];
#pragma unroll
    for (int dy = -1; dy <= 1; ++dy) {
        int yy = y + dy;
        if (yy < 0 || yy >= HH) continue;
#pragma unroll
        for (int dx = -1; dx <= 1; ++dx) {
            int xx = x + dx;
            if (xx < 0 || xx >= WW) continue;
            acc = fmaf(bf2f(p[yy * WW + xx]), wv[(dy + 1) * 3 + (dx + 1)], acc);
        }
    }
    out[(size_t)bc * NN + y * WW + x] = f2bf(acc);
}

// ---------- K3: per-row l2 norm scales. grid = 4*B*192, block 256 ----------
// sets: 0=ms_q 1=ms_k 2=sar_q 3=sar_k ; norms[set*768 + b*192 + c] = 1/max(||row||,eps)
__global__ __launch_bounds__(256) void k_norms(
    const uint16_t* __restrict__ qkv_ms, const uint16_t* __restrict__ qkv_sar,
    float* __restrict__ norms)
{
    const int t = threadIdx.x;
    const int bi = blockIdx.x;
    const int s = bi / 768;
    const int bc = bi % 768;
    const int b = bc / DIMC, c = bc % DIMC;
    const uint16_t* base = (s < 2) ? qkv_ms : qkv_sar;
    const uint16_t* row = base + ((size_t)b * D3 + (size_t)(s & 1) * DIMC + c) * NN;
    float sum = 0.f;
    for (int it = 0; it < 8; ++it) {
        uint4 u = *reinterpret_cast<const uint4*>(row + (it * 256 + t) * 8);
        uint32_t uu[4] = {u.x, u.y, u.z, u.w};
#pragma unroll
        for (int k = 0; k < 4; ++k) {
            float2 f = upk2(uu[k]);
            sum = fmaf(f.x, f.x, fmaf(f.y, f.y, sum));
        }
    }
#pragma unroll
    for (int o = 32; o > 0; o >>= 1) sum += __shfl_down(sum, o);
    __shared__ float red[4];
    if ((t & 63) == 0) red[t >> 6] = sum;
    __syncthreads();
    if (t == 0) {
        float tot = red[0] + red[1] + red[2] + red[3];
        norms[bi] = 1.0f / fmaxf(sqrtf(tot), 1e-12f);
    }
}

// ---------- K4a: partial raw scores over K-chunks ----------
// pid = (type*4+b)*4+h ; grid = 48*16 (16 chunks of 1024), block 256
// type0: ms_self (q=ms_q,k=ms_k)  type1: sar_self  type2: cross (q=sar_q,k=ms_k)
__global__ __launch_bounds__(256) void k_scores(
    const uint16_t* __restrict__ qkv_ms, const uint16_t* __restrict__ qkv_sar,
    float* __restrict__ partial)
{
    __shared__ uint16_t qs[CHD][136];
    __shared__ uint16_t ks[CHD][136];
    const int t = threadIdx.x;
    const int blk = blockIdx.x;
    const int ck = blk & 15;
    const int pid = blk >> 4;
    const int h = pid & 3, b2 = (pid >> 2) & 3, type = pid >> 4;
    const uint16_t* qsrc = (type == 0) ? qkv_ms : qkv_sar;
    const uint16_t* ksrc = (type == 1) ? qkv_sar : qkv_ms;
    const uint16_t* qb = qsrc + ((size_t)b2 * D3 + (size_t)h * CHD) * NN;
    const uint16_t* kb = ksrc + ((size_t)b2 * D3 + DIMC + (size_t)h * CHD) * NN;
    const int n0 = ck * 1024;
    const int tc = t >> 4, td = t & 15;
    float acc[3][3] = {};
    for (int sub = 0; sub < 8; ++sub) {
        __syncthreads();
        for (int i = t; i < CHD * 16; i += 256) {
            int r = i >> 4, f = i & 15;
            *reinterpret_cast<uint4*>(&qs[r][f * 8]) =
                *reinterpret_cast<const uint4*>(qb + (size_t)r * NN + n0 + sub * 128 + f * 8);
            *reinterpret_cast<uint4*>(&ks[r][f * 8]) =
                *reinterpret_cast<const uint4*>(kb + (size_t)r * NN + n0 + sub * 128 + f * 8);
        }
        __syncthreads();
#pragma unroll 8
        for (int n2 = 0; n2 < 64; ++n2) {
            const int n = n2 * 2;
            float2 qv[3], kv[3];
#pragma unroll
            for (int i = 0; i < 3; ++i)
                qv[i] = upk2(*reinterpret_cast<const uint32_t*>(&qs[tc + 16 * i][n]));
#pragma unroll
            for (int j = 0; j < 3; ++j)
                kv[j] = upk2(*reinterpret_cast<const uint32_t*>(&ks[td + 16 * j][n]));
#pragma unroll
            for (int i = 0; i < 3; ++i)
#pragma unroll
                for (int j = 0; j < 3; ++j)
                    acc[i][j] += qv[i].x * kv[j].x + qv[i].y * kv[j].y;
        }
    }
    float* pd = partial + ((size_t)pid * 16 + ck) * 2304;
#pragma unroll
    for (int i = 0; i < 3; ++i)
#pragma unroll
        for (int j = 0; j < 3; ++j)
            pd[(tc + 16 * i) * 48 + td + 16 * j] = acc[i][j];
}

// ---------- K4b: reduce chunks + scale + softmax. grid = 48*48, block 64 ----------
__global__ __launch_bounds__(64) void k_softmax(
    const float* __restrict__ partial, const float* __restrict__ norms,
    const float* __restrict__ ms_temp, const float* __restrict__ sar_temp,
    float* __restrict__ A)
{
    const int lane = threadIdx.x;
    const int bi = blockIdx.x;
    const int c = bi % 48;
    const int pid = bi / 48;
    const int h = pid & 3, b = (pid >> 2) & 3, type = pid >> 4;
    float s;
    if (lane < 48) {
        float accv = 0.f;
        const float* pp = partial + (size_t)pid * 16 * 2304 + c * 48 + lane;
#pragma unroll
        for (int ck = 0; ck < 16; ++ck) accv += pp[(size_t)ck * 2304];
        const int qset = (type == 0) ? 0 : 2;
        const int kset = (type == 1) ? 3 : 1;
        const float tval = (type == 1) ? sar_temp[h] : ms_temp[h];
        const float qsc = norms[qset * 768 + b * DIMC + h * CHD + c];
        const float ksc = norms[kset * 768 + b * DIMC + h * CHD + lane];
        s = accv * qsc * ksc * tval;
    } else {
        s = -3.0e38f;
    }
    float m = s;
#pragma unroll
    for (int o = 32; o > 0; o >>= 1) m = fmaxf(m, __shfl_xor(m, o));
    float e = (lane < 48) ? __expf(s - m) : 0.f;
    float sum = e;
#pragma unroll
    for (int o = 32; o > 0; o >>= 1) sum += __shfl_xor(sum, o);
    if (lane < 48) A[(size_t)pid * 2304 + c * 48 + lane] = e / sum;
}

// ---------- K5: out[c][n] = sum_d A[c][d] * v[d][n], bf16 out ----------
// grid = 48 pids * 32 (512-px tiles), block 256, 2 px/thread
__global__ __launch_bounds__(256) void k_apply(
    const float* __restrict__ A, const uint16_t* __restrict__ qkv_ms,
    const uint16_t* __restrict__ qkv_sar, uint16_t* __restrict__ attn)
{
    const int t = threadIdx.x;
    const int blk = blockIdx.x;
    const int nb = blk & 31;
    const int pid = blk >> 5;
    const int h = pid & 3, b = (pid >> 2) & 3, type = pid >> 4;
    const float* Ap = A + (size_t)pid * 2304;
    const uint16_t* vsrc = (type == 0) ? qkv_ms : qkv_sar;
    const uint16_t* vb = vsrc + ((size_t)b * D3 + 2 * DIMC + (size_t)h * CHD) * NN;
    const int n = nb * 512 + t * 2;
    float acc0[CHD], acc1[CHD];
#pragma unroll
    for (int c = 0; c < CHD; ++c) { acc0[c] = 0.f; acc1[c] = 0.f; }
    for (int d = 0; d < CHD; ++d) {
        float2 vv = upk2(*reinterpret_cast<const uint32_t*>(vb + (size_t)d * NN + n));
#pragma unroll
        for (int c = 0; c < CHD; ++c) {
            float a = Ap[c * 48 + d];
            acc0[c] = fmaf(a, vv.x, acc0[c]);
            acc1[c] = fmaf(a, vv.y, acc1[c]);
        }
    }
    uint16_t* ob = attn + (size_t)type * BB * DIMC * NN +
                   ((size_t)b * DIMC + (size_t)h * CHD) * NN + n;
#pragma unroll
    for (int c = 0; c < CHD; ++c) {
        uint32_t pk2 = (uint32_t)f2bf(acc0[c]) | ((uint32_t)f2bf(acc1[c]) << 16);
        *reinterpret_cast<uint32_t*>(ob + (size_t)c * NN) = pk2;
    }
}

// ---------- K6: sar proj + residual: out = sar + W @ sar_self + b ----------
__global__ __launch_bounds__(256) void k_proj_sar(
    const uint16_t* __restrict__ selfb, const float* __restrict__ w,
    const float* __restrict__ bias, const float* __restrict__ resid,
    float* __restrict__ out)
{
    __shared__ float xs[DIMC][64];
    const int t = threadIdx.x;
    const int b = blockIdx.x >> 8;
    const int n0 = (blockIdx.x & 255) * 64;
    const uint16_t* xb = selfb + ((size_t)b * DIMC) * NN + n0;
    for (int i = t; i < DIMC * 8; i += 256) {
        int c = i >> 3, f = i & 7;
        uint4 u = *reinterpret_cast<const uint4*>(xb + (size_t)c * NN + f * 8);
        uint32_t uu[4] = {u.x, u.y, u.z, u.w};
#pragma unroll
        for (int k = 0; k < 4; ++k) {
            float2 fv = upk2(uu[k]);
            xs[c][f * 8 + k * 2] = fv.x;
            xs[c][f * 8 + k * 2 + 1] = fv.y;
        }
    }
    __syncthreads();
    const int pt = t & 15, ot = t >> 4;
    for (int og = 0; og < 3; ++og) {
        const int oc0 = og * 64 + ot * 4;
        float acc[4][4];
#pragma unroll
        for (int i = 0; i < 4; ++i) {
            float bv = bias[oc0 + i];
#pragma unroll
            for (int j = 0; j < 4; ++j) acc[i][j] = bv;
        }
        const float* w0 = w + (size_t)oc0 * DIMC;
#pragma unroll 4
        for (int c = 0; c < DIMC; ++c) {
            float4 xv = *reinterpret_cast<const float4*>(&xs[c][pt * 4]);
#pragma unroll
            for (int i = 0; i < 4; ++i) {
                float wv = w0[i * DIMC + c];
                acc[i][0] = fmaf(wv, xv.x, acc[i][0]);
                acc[i][1] = fmaf(wv, xv.y, acc[i][1]);
                acc[i][2] = fmaf(wv, xv.z, acc[i][2]);
                acc[i][3] = fmaf(wv, xv.w, acc[i][3]);
            }
        }
#pragma unroll
        for (int i = 0; i < 4; ++i) {
            size_t o = ((size_t)b * DIMC + oc0 + i) * NN + n0 + pt * 4;
            float4 rv = *reinterpret_cast<const float4*>(resid + o);
            float4 w4;
            w4.x = rv.x + acc[i][0]; w4.y = rv.y + acc[i][1];
            w4.z = rv.z + acc[i][2]; w4.w = rv.w + acc[i][3];
            *reinterpret_cast<float4*>(out + o) = w4;
        }
    }
}

// ---------- K7: ms proj + residual over concat(ms_self, cross+ms_self) ----------
__global__ __launch_bounds__(256) void k_proj_ms(
    const uint16_t* __restrict__ selfb, const uint16_t* __restrict__ crossb,
    const float* __restrict__ w, const float* __restrict__ bias,
    const float* __restrict__ resid, float* __restrict__ out)
{
    __shared__ uint16_t xa[DIMC][64];
    __shared__ uint16_t xb2[DIMC][64];
    const int t = threadIdx.x;
    const int b = blockIdx.x >> 8;
    const int n0 = (blockIdx.x & 255) * 64;
    const uint16_t* pa = selfb + ((size_t)b * DIMC) * NN + n0;
    const uint16_t* pc = crossb + ((size_t)b * DIMC) * NN + n0;
    for (int i = t; i < DIMC * 8; i += 256) {
        int c = i >> 3, f = i & 7;
        uint4 ua = *reinterpret_cast<const uint4*>(pa + (size_t)c * NN + f * 8);
        uint4 uc = *reinterpret_cast<const uint4*>(pc + (size_t)c * NN + f * 8);
        *reinterpret_cast<uint4*>(&xa[c][f * 8]) = ua;
        uint32_t a4[4] = {ua.x, ua.y, ua.z, ua.w};
        uint32_t c4[4] = {uc.x, uc.y, uc.z, uc.w};
        ushort4 lo, hi;
        {
            float2 fa0 = upk2(a4[0]), fc0 = upk2(c4[0]);
            float2 fa1 = upk2(a4[1]), fc1 = upk2(c4[1]);
            lo.x = f2bf(fa0.x + fc0.x); lo.y = f2bf(fa0.y + fc0.y);
            lo.z = f2bf(fa1.x + fc1.x); lo.w = f2bf(fa1.y + fc1.y);
            float2 fa2 = upk2(a4[2]), fc2 = upk2(c4[2]);
            float2 fa3 = upk2(a4[3]), fc3 = upk2(c4[3]);
            hi.x = f2bf(fa2.x + fc2.x); hi.y = f2bf(fa2.y + fc2.y);
            hi.z = f2bf(fa3.x + fc3.x); hi.w = f2bf(fa3.y + fc3.y);
        }
        *reinterpret_cast<ushort4*>(&xb2[c][f * 8]) = lo;
        *reinterpret_cast<ushort4*>(&xb2[c][f * 8 + 4]) = hi;
    }
    __syncthreads();
    const int pt = t & 15, ot = t >> 4;
    for (int og = 0; og < 3; ++og) {
        const int oc0 = og * 64 + ot * 4;
        float acc[4][4];
#pragma unroll
        for (int i = 0; i < 4; ++i) {
            float bv = bias[oc0 + i];
#pragma unroll
            for (int j = 0; j < 4; ++j) acc[i][j] = bv;
        }
        const float* w0 = w + (size_t)oc0 * 384;
#pragma unroll 2
        for (int c = 0; c < DIMC; ++c) {
            float2 av0 = upk2(*reinterpret_cast<const uint32_t*>(&xa[c][pt * 4]));
            float2 av1 = upk2(*reinterpret_cast<const uint32_t*>(&xa[c][pt * 4 + 2]));
            float2 bv0 = upk2(*reinterpret_cast<const uint32_t*>(&xb2[c][pt * 4]));
            float2 bv1 = upk2(*reinterpret_cast<const uint32_t*>(&xb2[c][pt * 4 + 2]));
            float xav[4] = {av0.x, av0.y, av1.x, av1.y};
            float xbv[4] = {bv0.x, bv0.y, bv1.x, bv1.y};
#pragma unroll
            for (int i = 0; i < 4; ++i) {
                float wa = w0[i * 384 + c];
                float wb = w0[i * 384 + 192 + c];
#pragma unroll
                for (int j = 0; j < 4; ++j)
                    acc[i][j] = fmaf(wa, xav[j], fmaf(wb, xbv[j], acc[i][j]));
            }
        }
#pragma unroll
        for (int i = 0; i < 4; ++i) {
            size_t o = ((size_t)b * DIMC + oc0 + i) * NN + n0 + pt * 4;
            float4 rv = *reinterpret_cast<const float4*>(resid + o);
            float4 w4;
            w4.x = rv.x + acc[i][0]; w4.y = rv.y + acc[i][1];
            w4.z = rv.z + acc[i][2]; w4.w = rv.w + acc[i][3];
            *reinterpret_cast<float4*>(out + o) = w4;
        }
    }
}

extern "C" void kernel_launch(void* const* d_in, const int* in_sizes, int n_in,
                              void* d_out, int out_size, void* d_ws, size_t ws_size,
                              hipStream_t stream)
{
    const float* sar        = (const float*)d_in[0];
    const float* ms         = (const float*)d_in[1];
    const float* ms_qkv_w   = (const float*)d_in[2];
    const float* ms_qkv_b   = (const float*)d_in[3];
    const float* ms_dw_w    = (const float*)d_in[4];
    const float* ms_dw_b    = (const float*)d_in[5];
    const float* ms_temp    = (const float*)d_in[6];
    const float* sar_qkv_w  = (const float*)d_in[7];
    const float* sar_qkv_b  = (const float*)d_in[8];
    const float* sar_dw_w   = (const float*)d_in[9];
    const float* sar_dw_b   = (const float*)d_in[10];
    const float* sar_temp   = (const float*)d_in[11];
    const float* ms_proj_w  = (const float*)d_in[12];
    const float* ms_proj_b  = (const float*)d_in[13];
    const float* sar_proj_w = (const float*)d_in[14];
    const float* sar_proj_b = (const float*)d_in[15];

    char* ws = (char*)d_ws;
    // ws layout (bytes):
    //   [0,          75497472)  tmp bf16 (conv1x1 out) -> later reused for attn outs
    //   [75497472,  150994944)  qkv_ms bf16
    //   [150994944, 226492416)  qkv_sar bf16
    //   [226492416, 226504704)  norm scales f32 (4 sets x 4 x 192)
    //   [226504704, 233582592)  partial scores f32 (48 pid x 16 ck x 48 x 48)
    //   [233582592, 234024960)  softmaxed A f32 (48 pid x 48 x 48)
    uint16_t* tmp     = (uint16_t*)(ws);
    uint16_t* qkv_ms  = (uint16_t*)(ws + 75497472ull);
    uint16_t* qkv_sar = (uint16_t*)(ws + 150994944ull);
    float* norms      = (float*)(ws + 226492416ull);
    float* partial    = (float*)(ws + 226504704ull);
    float* Amat       = (float*)(ws + 233582592ull);
    uint16_t* attn    = tmp;  // tmp is dead after dwconv; reuse for attention outputs

    float* out_sar = (float*)d_out;
    float* out_ms  = out_sar + (size_t)BB * DIMC * NN;

    dim3 b256(256);
    k_conv_qkv<<<dim3(BB * 256), b256, 0, stream>>>(ms, ms_qkv_w, ms_qkv_b, tmp);
    k_dwconv<<<dim3(1, 64, BB * D3), dim3(128, 2), 0, stream>>>(tmp, ms_dw_w, ms_dw_b, qkv_ms);
    k_conv_qkv<<<dim3(BB * 256), b256, 0, stream>>>(sar, sar_qkv_w, sar_qkv_b, tmp);
    k_dwconv<<<dim3(1, 64, BB * D3), dim3(128, 2), 0, stream>>>(tmp, sar_dw_w, sar_dw_b, qkv_sar);
    k_norms<<<dim3(4 * BB * DIMC), b256, 0, stream>>>(qkv_ms, qkv_sar, norms);
    k_scores<<<dim3(48 * 16), b256, 0, stream>>>(qkv_ms, qkv_sar, partial);
    k_softmax<<<dim3(48 * 48), dim3(64), 0, stream>>>(partial, norms, ms_temp, sar_temp, Amat);
    k_apply<<<dim3(48 * 32), b256, 0, stream>>>(Amat, qkv_ms, qkv_sar, attn);

    uint16_t* ms_self  = attn;
    uint16_t* sar_self = attn + (size_t)BB * DIMC * NN;
    uint16_t* crossb   = attn + 2ull * BB * DIMC * NN;
    k_proj_sar<<<dim3(BB * 256), b256, 0, stream>>>(sar_self, sar_proj_w, sar_proj_b, sar, out_sar);
    k_proj_ms<<<dim3(BB * 256), b256, 0, stream>>>(ms_self, crossb, ms_proj_w, ms_proj_b, ms, out_ms);
}

// Round 2
// 690.084 us; speedup vs baseline: 2.2752x; 2.2752x over previous
//
#include <hip/hip_runtime.h>
#include <hip/hip_bf16.h>
#include <cstdint>

#define DIMC 192
#define BB 4
#define NN 16384
#define D3 576
#define CHD 48
#define WWID 128
#define HHGT 128

typedef short short8 __attribute__((ext_vector_type(8)));
typedef float f32x4 __attribute__((ext_vector_type(4)));

union FragU { uint4 u4; short8 s8; };

// ---------- bf16 helpers ----------
__device__ __forceinline__ float bf2f(uint16_t v) {
    return __uint_as_float(((uint32_t)v) << 16);
}
__device__ __forceinline__ float2 upk2(uint32_t u) {
    float2 r;
    r.x = __uint_as_float(u << 16);
    r.y = __uint_as_float(u & 0xffff0000u);
    return r;
}
__device__ __forceinline__ uint16_t f2bf(float f) {
    uint32_t x = __float_as_uint(f);
    return (uint16_t)((x + 0x7fffu + ((x >> 16) & 1u)) >> 16);
}
__device__ __forceinline__ uint4 pack8(const uint16_t* v) {
    uint4 u;
    u.x = (uint32_t)v[0] | ((uint32_t)v[1] << 16);
    u.y = (uint32_t)v[2] | ((uint32_t)v[3] << 16);
    u.z = (uint32_t)v[4] | ((uint32_t)v[5] << 16);
    u.w = (uint32_t)v[6] | ((uint32_t)v[7] << 16);
    return u;
}
// unit swizzle: 8-elem (16B) units within a 40-elem LDS row; breaks the
// period-8 bank cycle of the 80B row stride.
__device__ __forceinline__ int swu(int row, int u) { return u ^ ((row >> 3) & 3); }

// ---------- K0: weights fp32 -> bf16 ----------
__global__ __launch_bounds__(256) void k_prep(
    const float* __restrict__ w0, const float* __restrict__ w1,
    const float* __restrict__ w2, const float* __restrict__ w3,
    uint16_t* __restrict__ o0, uint16_t* __restrict__ o1,
    uint16_t* __restrict__ o2, uint16_t* __restrict__ o3)
{
    int i = blockIdx.x * 256 + threadIdx.x;
    if (i < 110592) { o0[i] = f2bf(w0[i]); return; }
    i -= 110592;
    if (i < 110592) { o1[i] = f2bf(w1[i]); return; }
    i -= 110592;
    if (i < 73728) { o2[i] = f2bf(w2[i]); return; }
    i -= 73728;
    if (i < 36864) o3[i] = f2bf(w3[i]);
}

// ---------- unified MFMA GEMM: out[M][N] = W[M][K] @ X[K][N] (+bias, +resid) ----------
// block 256 = 4 waves (2x2), tile 64(M) x 128(N), K-step 32.
// XFP32: X is fp32 (conv input). DUAL: K=384, rows<192 = Xa, rows>=192 = Xa+Xb.
// RESID: fp32 out with residual add; else bf16 out.
template<int KTOT, int MTOT, bool XFP32, bool DUAL, bool RESID>
__global__ __launch_bounds__(256) void k_gemm(
    const void* __restrict__ xa_, const uint16_t* __restrict__ xb,
    const uint16_t* __restrict__ wbf, const float* __restrict__ bias,
    const float* __restrict__ resid, void* __restrict__ out_)
{
    constexpr int MB = MTOT / 64;
    __shared__ uint16_t xs[128][40];   // X tile transposed: [n][k 0..31 + pad]
    __shared__ uint16_t wst[64][40];   // W tile: [m][k 0..31 + pad]
    const int t = threadIdx.x;
    int bid = blockIdx.x;
    const int mb = bid % MB; bid /= MB;
    const int nb = bid & 127; const int b = bid >> 7;
    const int m0 = mb * 64, n0 = nb * 128;

    const int lane = t & 63, wvid = t >> 6;
    const int lm = lane & 15, g = lane >> 4;
    const int wm = wvid >> 1, wn = wvid & 1;

    const int sn = t & 127;   // stage: n column
    const int skh = t >> 7;   // stage: k-half (16 rows)
    const int wm_ = t >> 2;   // W stage: m row
    const int wkq = t & 3;    // W stage: 8-k unit

    f32x4 acc[2][4];
#pragma unroll
    for (int i = 0; i < 2; ++i)
#pragma unroll
        for (int j = 0; j < 4; ++j) acc[i][j] = (f32x4){0.f, 0.f, 0.f, 0.f};

    const float* xaf = (const float*)xa_;
    const uint16_t* xab = (const uint16_t*)xa_;

    for (int k0 = 0; k0 < KTOT; k0 += 32) {
        __syncthreads();
        // ---- stage X (transpose in registers, 16 k-rows per thread) ----
        {
            uint16_t vals[16];
#pragma unroll
            for (int j = 0; j < 16; ++j) {
                const int kg = k0 + skh * 16 + j;
                if constexpr (XFP32) {
                    vals[j] = f2bf(xaf[((size_t)b * KTOT + kg) * NN + n0 + sn]);
                } else if constexpr (DUAL) {
                    const int kr = (kg < DIMC) ? kg : kg - DIMC;
                    const size_t off = ((size_t)b * DIMC + kr) * NN + n0 + sn;
                    float v = bf2f(xab[off]);
                    if (kg >= DIMC) v += bf2f(xb[off]);
                    vals[j] = f2bf(v);
                } else {
                    vals[j] = xab[((size_t)b * KTOT + kg) * NN + n0 + sn];
                }
            }
            *(uint4*)&xs[sn][swu(sn, 2 * skh) * 8]     = pack8(&vals[0]);
            *(uint4*)&xs[sn][swu(sn, 2 * skh + 1) * 8] = pack8(&vals[8]);
        }
        // ---- stage W ----
        {
            uint4 wv4 = *(const uint4*)&wbf[(size_t)(m0 + wm_) * KTOT + k0 + wkq * 8];
            *(uint4*)&wst[wm_][swu(wm_, wkq) * 8] = wv4;
        }
        __syncthreads();
        // ---- fragments + MFMA ----
        FragU afr[2], bfr[4];
#pragma unroll
        for (int mi = 0; mi < 2; ++mi) {
            const int row = wm * 32 + mi * 16 + lm;
            afr[mi].u4 = *(const uint4*)&wst[row][swu(row, g) * 8];
        }
#pragma unroll
        for (int nj = 0; nj < 4; ++nj) {
            const int row = wn * 64 + nj * 16 + lm;
            bfr[nj].u4 = *(const uint4*)&xs[row][swu(row, g) * 8];
        }
#pragma unroll
        for (int mi = 0; mi < 2; ++mi)
#pragma unroll
            for (int nj = 0; nj < 4; ++nj)
                acc[mi][nj] = __builtin_amdgcn_mfma_f32_16x16x32_bf16(
                    afr[mi].s8, bfr[nj].s8, acc[mi][nj], 0, 0, 0);
    }

    // ---- epilogue ----
#pragma unroll
    for (int mi = 0; mi < 2; ++mi) {
        const int rbase = m0 + wm * 32 + mi * 16 + g * 4;
        const float4 bv = *(const float4*)&bias[rbase];
        const float bva[4] = {bv.x, bv.y, bv.z, bv.w};
#pragma unroll
        for (int nj = 0; nj < 4; ++nj) {
            const int gcol = n0 + wn * 64 + nj * 16 + lm;
#pragma unroll
            for (int r = 0; r < 4; ++r) {
                const size_t idx = ((size_t)b * MTOT + rbase + r) * NN + gcol;
                const float v = acc[mi][nj][r] + bva[r];
                if constexpr (RESID) {
                    ((float*)out_)[idx] = resid[idx] + v;
                } else {
                    ((uint16_t*)out_)[idx] = f2bf(v);
                }
            }
        }
    }
}

// ---------- depthwise 3x3 + bias, 8 px/thread ----------
__global__ __launch_bounds__(256) void k_dwconv2(
    const uint16_t* __restrict__ in, const float* __restrict__ w9,
    const float* __restrict__ bias, uint16_t* __restrict__ out)
{
    const int t = threadIdx.x;
    const int bc = blockIdx.z;
    const int ch = bc % D3;
    const int xg = t & 15, yl = t >> 4;
    const int x0 = xg * 8;
    const int y = blockIdx.y * 16 + yl;
    const uint16_t* p = in + (size_t)bc * NN;
    float wv[9];
#pragma unroll
    for (int k = 0; k < 9; ++k) wv[k] = w9[ch * 9 + k];
    float r[3][10];
#pragma unroll
    for (int dy = 0; dy < 3; ++dy) {
        const int yy = y + dy - 1;
        if (yy < 0 || yy >= HHGT) {
#pragma unroll
            for (int j = 0; j < 10; ++j) r[dy][j] = 0.f;
        } else {
            const uint16_t* row = p + yy * WWID;
            uint4 u = *(const uint4*)(row + x0);
            const uint16_t* pv = (const uint16_t*)&u;
#pragma unroll
            for (int j = 0; j < 8; ++j) r[dy][j + 1] = bf2f(pv[j]);
            r[dy][0] = (x0 > 0) ? bf2f(row[x0 - 1]) : 0.f;
            r[dy][9] = (x0 + 8 < WWID) ? bf2f(row[x0 + 8]) : 0.f;
        }
    }
    const float base = bias[ch];
    uint16_t ov[8];
#pragma unroll
    for (int j = 0; j < 8; ++j) {
        float a = base;
#pragma unroll
        for (int dy = 0; dy < 3; ++dy)
#pragma unroll
            for (int dx = 0; dx < 3; ++dx)
                a = fmaf(r[dy][j + dx], wv[dy * 3 + dx], a);
        ov[j] = f2bf(a);
    }
    *(uint4*)(out + (size_t)bc * NN + y * WWID + x0) = pack8(ov);
}

// ---------- per-row l2 norm scales ----------
__global__ __launch_bounds__(256) void k_norms(
    const uint16_t* __restrict__ qkv_ms, const uint16_t* __restrict__ qkv_sar,
    float* __restrict__ norms)
{
    const int t = threadIdx.x;
    const int bi = blockIdx.x;
    const int s = bi / 768;
    const int bc = bi % 768;
    const int b = bc / DIMC, c = bc % DIMC;
    const uint16_t* base = (s < 2) ? qkv_ms : qkv_sar;
    const uint16_t* row = base + ((size_t)b * D3 + (size_t)(s & 1) * DIMC + c) * NN;
    float sum = 0.f;
    for (int it = 0; it < 8; ++it) {
        uint4 u = *reinterpret_cast<const uint4*>(row + (it * 256 + t) * 8);
        uint32_t uu[4] = {u.x, u.y, u.z, u.w};
#pragma unroll
        for (int k = 0; k < 4; ++k) {
            float2 f = upk2(uu[k]);
            sum = fmaf(f.x, f.x, fmaf(f.y, f.y, sum));
        }
    }
#pragma unroll
    for (int o = 32; o > 0; o >>= 1) sum += __shfl_down(sum, o);
    __shared__ float red[4];
    if ((t & 63) == 0) red[t >> 6] = sum;
    __syncthreads();
    if (t == 0) {
        float tot = red[0] + red[1] + red[2] + red[3];
        norms[bi] = 1.0f / fmaxf(sqrtf(tot), 1e-12f);
    }
}

// ---------- partial raw scores, 8 chunks of 2048 ----------
__global__ __launch_bounds__(256) void k_scores(
    const uint16_t* __restrict__ qkv_ms, const uint16_t* __restrict__ qkv_sar,
    float* __restrict__ partial)
{
    __shared__ uint16_t qs[CHD][136];
    __shared__ uint16_t ks[CHD][136];
    const int t = threadIdx.x;
    const int blk = blockIdx.x;
    const int ck = blk & 7;
    const int pid = blk >> 3;
    const int h = pid & 3, b2 = (pid >> 2) & 3, type = pid >> 4;
    const uint16_t* qsrc = (type == 0) ? qkv_ms : qkv_sar;
    const uint16_t* ksrc = (type == 1) ? qkv_sar : qkv_ms;
    const uint16_t* qb = qsrc + ((size_t)b2 * D3 + (size_t)h * CHD) * NN;
    const uint16_t* kb = ksrc + ((size_t)b2 * D3 + DIMC + (size_t)h * CHD) * NN;
    const int n0 = ck * 2048;
    const int tc = t >> 4, td = t & 15;
    float acc[3][3] = {};
    for (int sub = 0; sub < 16; ++sub) {
        __syncthreads();
        for (int i = t; i < CHD * 16; i += 256) {
            int r = i >> 4, f = i & 15;
            *reinterpret_cast<uint4*>(&qs[r][f * 8]) =
                *reinterpret_cast<const uint4*>(qb + (size_t)r * NN + n0 + sub * 128 + f * 8);
            *reinterpret_cast<uint4*>(&ks[r][f * 8]) =
                *reinterpret_cast<const uint4*>(kb + (size_t)r * NN + n0 + sub * 128 + f * 8);
        }
        __syncthreads();
#pragma unroll 8
        for (int n2 = 0; n2 < 64; ++n2) {
            const int n = n2 * 2;
            float2 qv[3], kv[3];
#pragma unroll
            for (int i = 0; i < 3; ++i)
                qv[i] = upk2(*reinterpret_cast<const uint32_t*>(&qs[tc + 16 * i][n]));
#pragma unroll
            for (int j = 0; j < 3; ++j)
                kv[j] = upk2(*reinterpret_cast<const uint32_t*>(&ks[td + 16 * j][n]));
#pragma unroll
            for (int i = 0; i < 3; ++i)
#pragma unroll
                for (int j = 0; j < 3; ++j)
                    acc[i][j] += qv[i].x * kv[j].x + qv[i].y * kv[j].y;
        }
    }
    float* pd = partial + ((size_t)pid * 8 + ck) * 2304;
#pragma unroll
    for (int i = 0; i < 3; ++i)
#pragma unroll
        for (int j = 0; j < 3; ++j)
            pd[(tc + 16 * i) * 48 + td + 16 * j] = acc[i][j];
}

// ---------- reduce chunks + scale + softmax ----------
__global__ __launch_bounds__(64) void k_softmax(
    const float* __restrict__ partial, const float* __restrict__ norms,
    const float* __restrict__ ms_temp, const float* __restrict__ sar_temp,
    float* __restrict__ A)
{
    const int lane = threadIdx.x;
    const int bi = blockIdx.x;
    const int c = bi % 48;
    const int pid = bi / 48;
    const int h = pid & 3, b = (pid >> 2) & 3, type = pid >> 4;
    float s;
    if (lane < 48) {
        float accv = 0.f;
        const float* pp = partial + (size_t)pid * 8 * 2304 + c * 48 + lane;
#pragma unroll
        for (int ck = 0; ck < 8; ++ck) accv += pp[(size_t)ck * 2304];
        const int qset = (type == 0) ? 0 : 2;
        const int kset = (type == 1) ? 3 : 1;
        const float tval = (type == 1) ? sar_temp[h] : ms_temp[h];
        const float qsc = norms[qset * 768 + b * DIMC + h * CHD + c];
        const float ksc = norms[kset * 768 + b * DIMC + h * CHD + lane];
        s = accv * qsc * ksc * tval;
    } else {
        s = -3.0e38f;
    }
    float m = s;
#pragma unroll
    for (int o = 32; o > 0; o >>= 1) m = fmaxf(m, __shfl_xor(m, o));
    float e = (lane < 48) ? __expf(s - m) : 0.f;
    float sum = e;
#pragma unroll
    for (int o = 32; o > 0; o >>= 1) sum += __shfl_xor(sum, o);
    if (lane < 48) A[(size_t)pid * 2304 + c * 48 + lane] = e / sum;
}

// ---------- MFMA apply: out[c][n] = sum_d A[c][d] V[d][n] ----------
// block 256 (4 waves), tile M=48 x N=256, K=48 zero-padded to 64.
__global__ __launch_bounds__(256) void k_apply_mfma(
    const float* __restrict__ A, const uint16_t* __restrict__ qkv_ms,
    const uint16_t* __restrict__ qkv_sar, uint16_t* __restrict__ attn)
{
    __shared__ uint16_t vs[256][40];
    __shared__ uint16_t as[48][40];
    const int t = threadIdx.x;
    const int nb = blockIdx.x & 63;
    const int pid = blockIdx.x >> 6;
    const int h = pid & 3, b = (pid >> 2) & 3, type = pid >> 4;
    const int n0 = nb * 256;
    const uint16_t* vsrc = (type == 0) ? qkv_ms : qkv_sar;
    const uint16_t* vb = vsrc + ((size_t)b * D3 + 2 * DIMC + (size_t)h * CHD) * NN;
    const float* Ap = A + (size_t)pid * 2304;

    const int lane = t & 63, wvid = t >> 6;
    const int lm = lane & 15, g = lane >> 4;

    f32x4 acc[3][4];
#pragma unroll
    for (int i = 0; i < 3; ++i)
#pragma unroll
        for (int j = 0; j < 4; ++j) acc[i][j] = (f32x4){0.f, 0.f, 0.f, 0.f};

    for (int k0 = 0; k0 < 64; k0 += 32) {
        __syncthreads();
        // stage V rows (zero-pad d>=48)
#pragma unroll
        for (int kh = 0; kh < 2; ++kh) {
            uint16_t vals[16];
#pragma unroll
            for (int j = 0; j < 16; ++j) {
                const int d = k0 + kh * 16 + j;
                vals[j] = (d < CHD) ? vb[(size_t)d * NN + n0 + t] : (uint16_t)0;
            }
            *(uint4*)&vs[t][swu(t, 2 * kh) * 8]     = pack8(&vals[0]);
            *(uint4*)&vs[t][swu(t, 2 * kh + 1) * 8] = pack8(&vals[8]);
        }
        // stage A rows (fp32 -> bf16, zero-pad)
        if (t < 192) {
            const int c = t >> 2, dq = t & 3;
            uint16_t av[8];
#pragma unroll
            for (int i = 0; i < 8; ++i) {
                const int d = k0 + dq * 8 + i;
                av[i] = (d < CHD) ? f2bf(Ap[c * CHD + d]) : (uint16_t)0;
            }
            *(uint4*)&as[c][swu(c, dq) * 8] = pack8(av);
        }
        __syncthreads();
        FragU afr[3], bfr[4];
#pragma unroll
        for (int mi = 0; mi < 3; ++mi) {
            const int row = mi * 16 + lm;
            afr[mi].u4 = *(const uint4*)&as[row][swu(row, g) * 8];
        }
#pragma unroll
        for (int nj = 0; nj < 4; ++nj) {
            const int row = wvid * 64 + nj * 16 + lm;
            bfr[nj].u4 = *(const uint4*)&vs[row][swu(row, g) * 8];
        }
#pragma unroll
        for (int mi = 0; mi < 3; ++mi)
#pragma unroll
            for (int nj = 0; nj < 4; ++nj)
                acc[mi][nj] = __builtin_amdgcn_mfma_f32_16x16x32_bf16(
                    afr[mi].s8, bfr[nj].s8, acc[mi][nj], 0, 0, 0);
    }

    uint16_t* ob = attn + (size_t)type * BB * DIMC * NN +
                   ((size_t)b * DIMC + (size_t)h * CHD) * NN;
#pragma unroll
    for (int mi = 0; mi < 3; ++mi) {
        const int rbase = mi * 16 + g * 4;
#pragma unroll
        for (int nj = 0; nj < 4; ++nj) {
            const int gcol = n0 + wvid * 64 + nj * 16 + lm;
#pragma unroll
            for (int r = 0; r < 4; ++r)
                ob[(size_t)(rbase + r) * NN + gcol] = f2bf(acc[mi][nj][r]);
        }
    }
}

extern "C" void kernel_launch(void* const* d_in, const int* in_sizes, int n_in,
                              void* d_out, int out_size, void* d_ws, size_t ws_size,
                              hipStream_t stream)
{
    const float* sar        = (const float*)d_in[0];
    const float* ms         = (const float*)d_in[1];
    const float* ms_qkv_w   = (const float*)d_in[2];
    const float* ms_qkv_b   = (const float*)d_in[3];
    const float* ms_dw_w    = (const float*)d_in[4];
    const float* ms_dw_b    = (const float*)d_in[5];
    const float* ms_temp    = (const float*)d_in[6];
    const float* sar_qkv_w  = (const float*)d_in[7];
    const float* sar_qkv_b  = (const float*)d_in[8];
    const float* sar_dw_w   = (const float*)d_in[9];
    const float* sar_dw_b   = (const float*)d_in[10];
    const float* sar_temp   = (const float*)d_in[11];
    const float* ms_proj_w  = (const float*)d_in[12];
    const float* ms_proj_b  = (const float*)d_in[13];
    const float* sar_proj_w = (const float*)d_in[14];
    const float* sar_proj_b = (const float*)d_in[15];

    char* ws = (char*)d_ws;
    // ws layout (bytes) — fits within round-1's proven 234,024,960 footprint:
    //   [0,          75497472)  tmp bf16 (conv1x1 out) -> reused for attn outs
    //   [75497472,  150994944)  qkv_ms bf16
    //   [150994944, 226492416)  qkv_sar bf16
    //   [226492416, 226504704)  norm scales f32
    //   [226504704, 230043648)  partial scores f32 (48 pid x 8 ck x 2304)
    //   [230043648, 230486016)  softmaxed A f32 (48 pid x 2304)
    //   [230486016, 231149568)  bf16 weights (qkv_ms, qkv_sar, proj_ms, proj_sar)
    uint16_t* tmp     = (uint16_t*)(ws);
    uint16_t* qkv_ms  = (uint16_t*)(ws + 75497472ull);
    uint16_t* qkv_sar = (uint16_t*)(ws + 150994944ull);
    float* norms      = (float*)(ws + 226492416ull);
    float* partial    = (float*)(ws + 226504704ull);
    float* Amat       = (float*)(ws + 230043648ull);
    uint16_t* wq_ms   = (uint16_t*)(ws + 230486016ull);
    uint16_t* wq_sar  = (uint16_t*)(ws + 230707200ull);
    uint16_t* wp_ms   = (uint16_t*)(ws + 230928384ull);
    uint16_t* wp_sar  = (uint16_t*)(ws + 231075840ull);
    uint16_t* attn    = tmp;

    float* out_sar = (float*)d_out;
    float* out_ms  = out_sar + (size_t)BB * DIMC * NN;

    dim3 b256(256);
    k_prep<<<dim3(1296), b256, 0, stream>>>(ms_qkv_w, sar_qkv_w, ms_proj_w, sar_proj_w,
                                            wq_ms, wq_sar, wp_ms, wp_sar);
    // ms qkv: conv1x1 (MFMA) + dwconv
    k_gemm<192, 576, true, false, false><<<dim3(9 * 128 * BB), b256, 0, stream>>>(
        ms, nullptr, wq_ms, ms_qkv_b, nullptr, tmp);
    k_dwconv2<<<dim3(1, 8, BB * D3), b256, 0, stream>>>(tmp, ms_dw_w, ms_dw_b, qkv_ms);
    // sar qkv
    k_gemm<192, 576, true, false, false><<<dim3(9 * 128 * BB), b256, 0, stream>>>(
        sar, nullptr, wq_sar, sar_qkv_b, nullptr, tmp);
    k_dwconv2<<<dim3(1, 8, BB * D3), b256, 0, stream>>>(tmp, sar_dw_w, sar_dw_b, qkv_sar);

    k_norms<<<dim3(4 * BB * DIMC), b256, 0, stream>>>(qkv_ms, qkv_sar, norms);
    k_scores<<<dim3(48 * 8), b256, 0, stream>>>(qkv_ms, qkv_sar, partial);
    k_softmax<<<dim3(48 * 48), dim3(64), 0, stream>>>(partial, norms, ms_temp, sar_temp, Amat);
    k_apply_mfma<<<dim3(48 * 64), b256, 0, stream>>>(Amat, qkv_ms, qkv_sar, attn);

    uint16_t* ms_self  = attn;
    uint16_t* sar_self = attn + (size_t)BB * DIMC * NN;
    uint16_t* crossb   = attn + 2ull * BB * DIMC * NN;
    k_gemm<192, 192, false, false, true><<<dim3(3 * 128 * BB), b256, 0, stream>>>(
        sar_self, nullptr, wp_sar, sar_proj_b, sar, out_sar);
    k_gemm<384, 192, false, true, true><<<dim3(3 * 128 * BB), b256, 0, stream>>>(
        ms_self, crossb, wp_ms, ms_proj_b, ms, out_ms);
}

// Round 3
// 417.606 us; speedup vs baseline: 3.7598x; 1.6525x over previous
//
#include <hip/hip_runtime.h>
#include <hip/hip_bf16.h>
#include <cstdint>

#define DIMC 192
#define BB 4
#define NN 16384
#define D3 576
#define CHD 48
#define WWID 128
#define HHGT 128

typedef short short8 __attribute__((ext_vector_type(8)));
typedef float f32x4 __attribute__((ext_vector_type(4)));

union FragU { uint4 u4; short8 s8; };

// ---------- bf16 helpers ----------
__device__ __forceinline__ float bf2f(uint16_t v) {
    return __uint_as_float(((uint32_t)v) << 16);
}
__device__ __forceinline__ float2 upk2(uint32_t u) {
    float2 r;
    r.x = __uint_as_float(u << 16);
    r.y = __uint_as_float(u & 0xffff0000u);
    return r;
}
__device__ __forceinline__ uint16_t f2bf(float f) {
    uint32_t x = __float_as_uint(f);
    return (uint16_t)((x + 0x7fffu + ((x >> 16) & 1u)) >> 16);
}
__device__ __forceinline__ uint4 pack8(const uint16_t* v) {
    uint4 u;
    u.x = (uint32_t)v[0] | ((uint32_t)v[1] << 16);
    u.y = (uint32_t)v[2] | ((uint32_t)v[3] << 16);
    u.z = (uint32_t)v[4] | ((uint32_t)v[5] << 16);
    u.w = (uint32_t)v[6] | ((uint32_t)v[7] << 16);
    return u;
}

// ---------- K0: weights fp32 -> bf16 (+ folded proj_ms weights) ----------
// wp1_ms = Wa+Wb (applies to ms_self), wp2_ms = Wb (applies to cross):
// W @ concat(self, cross+self) == (Wa+Wb)@self + Wb@cross
__global__ __launch_bounds__(256) void k_prep(
    const float* __restrict__ w0, const float* __restrict__ w1,
    const float* __restrict__ w2, const float* __restrict__ w3,
    uint16_t* __restrict__ o0, uint16_t* __restrict__ o1,
    uint16_t* __restrict__ o2a, uint16_t* __restrict__ o2b,
    uint16_t* __restrict__ o3)
{
    int i = blockIdx.x * 256 + threadIdx.x;
    if (i < 110592) { o0[i] = f2bf(w0[i]); return; }
    i -= 110592;
    if (i < 110592) { o1[i] = f2bf(w1[i]); return; }
    i -= 110592;
    if (i < 36864) {
        const int o = i / DIMC, c = i % DIMC;
        o2a[i] = f2bf(w2[o * 384 + c] + w2[o * 384 + DIMC + c]);
        o2b[i] = f2bf(w2[o * 384 + DIMC + c]);
        return;
    }
    i -= 36864;
    if (i < 36864) o3[i] = f2bf(w3[i]);
}

// ---------- qkv conv1x1 MFMA: out[576][NN] = W[576][192] @ X[192][NN], bf16 out ----------
// block 256 = 4 waves (2x2 over 64x128 sub-tile). One block owns a 128-col strip,
// full K=192 resident in LDS; B-fragments hoisted to VGPR once; loop 9 m-blocks.
__global__ __launch_bounds__(256, 2) void k_conv_mfma(
    const float* __restrict__ x, const uint16_t* __restrict__ wbf,
    const float* __restrict__ bias, uint16_t* __restrict__ out)
{
    __shared__ uint16_t xs[128][200];   // [n][k], 400B row stride -> 2-way max
    __shared__ uint16_t wst[64][200];   // [m][k]
    const int t = threadIdx.x;
    const int nb = blockIdx.x & 127;
    const int b = blockIdx.x >> 7;
    const int n0 = nb * 128;

    const int lane = t & 63, wvid = t >> 6;
    const int lm = lane & 15, g = lane >> 4;
    const int wm = wvid >> 1, wn = wvid & 1;

    // ---- stage X once: fp32 -> bf16, transposed to [n][k] ----
    {
        const int sn = t & 127, kh = t >> 7;
        const float* xcol = x + ((size_t)b * DIMC + kh * 96) * NN + n0 + sn;
        for (int u = 0; u < 12; ++u) {
            uint16_t vals[8];
#pragma unroll
            for (int j = 0; j < 8; ++j)
                vals[j] = f2bf(xcol[(size_t)(u * 8 + j) * NN]);
            *(uint4*)&xs[sn][(kh * 12 + u) * 8] = pack8(vals);
        }
    }
    // ---- stage W m-block 0 ----
    {
        const int wm_ = t >> 2, wq = t & 3;
        const uint16_t* wrow = wbf + (size_t)wm_ * DIMC;
#pragma unroll
        for (int i = 0; i < 6; ++i) {
            const int unit = i * 4 + wq;
            *(uint4*)&wst[wm_][unit * 8] = *(const uint4*)&wrow[unit * 8];
        }
    }
    __syncthreads();

    // ---- hoist B fragments (reused across all 9 m-blocks) ----
    FragU bfr[6][4];
#pragma unroll
    for (int ks = 0; ks < 6; ++ks)
#pragma unroll
        for (int nj = 0; nj < 4; ++nj) {
            const int row = wn * 64 + nj * 16 + lm;
            bfr[ks][nj].u4 = *(const uint4*)&xs[row][ks * 32 + g * 8];
        }

    for (int mb = 0; mb < 9; ++mb) {
        if (mb) {
            __syncthreads();
            const int wm_ = t >> 2, wq = t & 3;
            const uint16_t* wrow = wbf + (size_t)(mb * 64 + wm_) * DIMC;
#pragma unroll
            for (int i = 0; i < 6; ++i) {
                const int unit = i * 4 + wq;
                *(uint4*)&wst[wm_][unit * 8] = *(const uint4*)&wrow[unit * 8];
            }
            __syncthreads();
        }
        f32x4 acc[2][4];
#pragma unroll
        for (int mi = 0; mi < 2; ++mi)
#pragma unroll
            for (int nj = 0; nj < 4; ++nj) acc[mi][nj] = (f32x4){0.f, 0.f, 0.f, 0.f};
#pragma unroll
        for (int ks = 0; ks < 6; ++ks) {
            FragU afr[2];
#pragma unroll
            for (int mi = 0; mi < 2; ++mi) {
                const int row = wm * 32 + mi * 16 + lm;
                afr[mi].u4 = *(const uint4*)&wst[row][ks * 32 + g * 8];
            }
#pragma unroll
            for (int mi = 0; mi < 2; ++mi)
#pragma unroll
                for (int nj = 0; nj < 4; ++nj)
                    acc[mi][nj] = __builtin_amdgcn_mfma_f32_16x16x32_bf16(
                        afr[mi].s8, bfr[ks][nj].s8, acc[mi][nj], 0, 0, 0);
        }
        // epilogue for this m-block
#pragma unroll
        for (int mi = 0; mi < 2; ++mi) {
            const int rbase = mb * 64 + wm * 32 + mi * 16 + g * 4;
            const float4 bv = *(const float4*)&bias[rbase];
            const float bva[4] = {bv.x, bv.y, bv.z, bv.w};
#pragma unroll
            for (int nj = 0; nj < 4; ++nj) {
                const int gcol = n0 + wn * 64 + nj * 16 + lm;
#pragma unroll
                for (int r = 0; r < 4; ++r)
                    out[((size_t)b * D3 + rbase + r) * NN + gcol] =
                        f2bf(acc[mi][nj][r] + bva[r]);
            }
        }
    }
}

// ---------- proj MFMA: out[192][NN] = sum_ph W_ph[192][192] @ X_ph[192][NN] + resid ----------
template<int PHASES>
__global__ __launch_bounds__(256, 2) void k_proj_mfma(
    const uint16_t* __restrict__ x0, const uint16_t* __restrict__ x1,
    const uint16_t* __restrict__ w0, const uint16_t* __restrict__ w1,
    const float* __restrict__ bias, const float* __restrict__ resid,
    float* __restrict__ out)
{
    __shared__ uint16_t xs[128][200];
    __shared__ uint16_t wst[64][200];
    const int t = threadIdx.x;
    const int nb = blockIdx.x & 127;
    const int b = blockIdx.x >> 7;
    const int n0 = nb * 128;

    const int lane = t & 63, wvid = t >> 6;
    const int lm = lane & 15, g = lane >> 4;
    const int wm = wvid >> 1, wn = wvid & 1;

    f32x4 acc[3][2][4];
#pragma unroll
    for (int mb = 0; mb < 3; ++mb)
#pragma unroll
        for (int mi = 0; mi < 2; ++mi)
#pragma unroll
            for (int nj = 0; nj < 4; ++nj) acc[mb][mi][nj] = (f32x4){0.f, 0.f, 0.f, 0.f};

    for (int ph = 0; ph < PHASES; ++ph) {
        const uint16_t* xsrc = ph ? x1 : x0;
        const uint16_t* wsrc = ph ? w1 : w0;
        if (ph) __syncthreads();
        // stage X (bf16, transpose to [n][k])
        {
            const int sn = t & 127, kh = t >> 7;
            const uint16_t* xcol = xsrc + ((size_t)b * DIMC + kh * 96) * NN + n0 + sn;
            for (int u = 0; u < 12; ++u) {
                uint16_t vals[8];
#pragma unroll
                for (int j = 0; j < 8; ++j)
                    vals[j] = xcol[(size_t)(u * 8 + j) * NN];
                *(uint4*)&xs[sn][(kh * 12 + u) * 8] = pack8(vals);
            }
        }
        // stage W m-block 0
        {
            const int wm_ = t >> 2, wq = t & 3;
            const uint16_t* wrow = wsrc + (size_t)wm_ * DIMC;
#pragma unroll
            for (int i = 0; i < 6; ++i) {
                const int unit = i * 4 + wq;
                *(uint4*)&wst[wm_][unit * 8] = *(const uint4*)&wrow[unit * 8];
            }
        }
        __syncthreads();
        FragU bfr[6][4];
#pragma unroll
        for (int ks = 0; ks < 6; ++ks)
#pragma unroll
            for (int nj = 0; nj < 4; ++nj) {
                const int row = wn * 64 + nj * 16 + lm;
                bfr[ks][nj].u4 = *(const uint4*)&xs[row][ks * 32 + g * 8];
            }
        for (int mb = 0; mb < 3; ++mb) {
            if (mb) {
                __syncthreads();
                const int wm_ = t >> 2, wq = t & 3;
                const uint16_t* wrow = wsrc + (size_t)(mb * 64 + wm_) * DIMC;
#pragma unroll
                for (int i = 0; i < 6; ++i) {
                    const int unit = i * 4 + wq;
                    *(uint4*)&wst[wm_][unit * 8] = *(const uint4*)&wrow[unit * 8];
                }
                __syncthreads();
            }
#pragma unroll
            for (int ks = 0; ks < 6; ++ks) {
                FragU afr[2];
#pragma unroll
                for (int mi = 0; mi < 2; ++mi) {
                    const int row = wm * 32 + mi * 16 + lm;
                    afr[mi].u4 = *(const uint4*)&wst[row][ks * 32 + g * 8];
                }
#pragma unroll
                for (int mi = 0; mi < 2; ++mi)
#pragma unroll
                    for (int nj = 0; nj < 4; ++nj)
                        acc[mb][mi][nj] = __builtin_amdgcn_mfma_f32_16x16x32_bf16(
                            afr[mi].s8, bfr[ks][nj].s8, acc[mb][mi][nj], 0, 0, 0);
            }
        }
    }
    // epilogue: bias + residual, fp32 out
#pragma unroll
    for (int mb = 0; mb < 3; ++mb)
#pragma unroll
        for (int mi = 0; mi < 2; ++mi) {
            const int rbase = mb * 64 + wm * 32 + mi * 16 + g * 4;
            const float4 bv = *(const float4*)&bias[rbase];
            const float bva[4] = {bv.x, bv.y, bv.z, bv.w};
#pragma unroll
            for (int nj = 0; nj < 4; ++nj) {
                const int gcol = n0 + wn * 64 + nj * 16 + lm;
#pragma unroll
                for (int r = 0; r < 4; ++r) {
                    const size_t idx = ((size_t)b * DIMC + rbase + r) * NN + gcol;
                    out[idx] = resid[idx] + acc[mb][mi][nj][r] + bva[r];
                }
            }
        }
}

// ---------- depthwise 3x3 + bias, 8 px/thread ----------
__global__ __launch_bounds__(256) void k_dwconv2(
    const uint16_t* __restrict__ in, const float* __restrict__ w9,
    const float* __restrict__ bias, uint16_t* __restrict__ out)
{
    const int t = threadIdx.x;
    const int bc = blockIdx.z;
    const int ch = bc % D3;
    const int xg = t & 15, yl = t >> 4;
    const int x0 = xg * 8;
    const int y = blockIdx.y * 16 + yl;
    const uint16_t* p = in + (size_t)bc * NN;
    float wv[9];
#pragma unroll
    for (int k = 0; k < 9; ++k) wv[k] = w9[ch * 9 + k];
    float r[3][10];
#pragma unroll
    for (int dy = 0; dy < 3; ++dy) {
        const int yy = y + dy - 1;
        if (yy < 0 || yy >= HHGT) {
#pragma unroll
            for (int j = 0; j < 10; ++j) r[dy][j] = 0.f;
        } else {
            const uint16_t* row = p + yy * WWID;
            uint4 u = *(const uint4*)(row + x0);
            const uint16_t* pv = (const uint16_t*)&u;
#pragma unroll
            for (int j = 0; j < 8; ++j) r[dy][j + 1] = bf2f(pv[j]);
            r[dy][0] = (x0 > 0) ? bf2f(row[x0 - 1]) : 0.f;
            r[dy][9] = (x0 + 8 < WWID) ? bf2f(row[x0 + 8]) : 0.f;
        }
    }
    const float base = bias[ch];
    uint16_t ov[8];
#pragma unroll
    for (int j = 0; j < 8; ++j) {
        float a = base;
#pragma unroll
        for (int dy = 0; dy < 3; ++dy)
#pragma unroll
            for (int dx = 0; dx < 3; ++dx)
                a = fmaf(r[dy][j + dx], wv[dy * 3 + dx], a);
        ov[j] = f2bf(a);
    }
    *(uint4*)(out + (size_t)bc * NN + y * WWID + x0) = pack8(ov);
}

// ---------- per-row l2 norm scales ----------
__global__ __launch_bounds__(256) void k_norms(
    const uint16_t* __restrict__ qkv_ms, const uint16_t* __restrict__ qkv_sar,
    float* __restrict__ norms)
{
    const int t = threadIdx.x;
    const int bi = blockIdx.x;
    const int s = bi / 768;
    const int bc = bi % 768;
    const int b = bc / DIMC, c = bc % DIMC;
    const uint16_t* base = (s < 2) ? qkv_ms : qkv_sar;
    const uint16_t* row = base + ((size_t)b * D3 + (size_t)(s & 1) * DIMC + c) * NN;
    float sum = 0.f;
    for (int it = 0; it < 8; ++it) {
        uint4 u = *reinterpret_cast<const uint4*>(row + (it * 256 + t) * 8);
        uint32_t uu[4] = {u.x, u.y, u.z, u.w};
#pragma unroll
        for (int k = 0; k < 4; ++k) {
            float2 f = upk2(uu[k]);
            sum = fmaf(f.x, f.x, fmaf(f.y, f.y, sum));
        }
    }
#pragma unroll
    for (int o = 32; o > 0; o >>= 1) sum += __shfl_down(sum, o);
    __shared__ float red[4];
    if ((t & 63) == 0) red[t >> 6] = sum;
    __syncthreads();
    if (t == 0) {
        float tot = red[0] + red[1] + red[2] + red[3];
        norms[bi] = 1.0f / fmaxf(sqrtf(tot), 1e-12f);
    }
}

// ---------- partial raw scores, 8 chunks of 2048 ----------
__global__ __launch_bounds__(256) void k_scores(
    const uint16_t* __restrict__ qkv_ms, const uint16_t* __restrict__ qkv_sar,
    float* __restrict__ partial)
{
    __shared__ uint16_t qs[CHD][136];
    __shared__ uint16_t ks[CHD][136];
    const int t = threadIdx.x;
    const int blk = blockIdx.x;
    const int ck = blk & 7;
    const int pid = blk >> 3;
    const int h = pid & 3, b2 = (pid >> 2) & 3, type = pid >> 4;
    const uint16_t* qsrc = (type == 0) ? qkv_ms : qkv_sar;
    const uint16_t* ksrc = (type == 1) ? qkv_sar : qkv_ms;
    const uint16_t* qb = qsrc + ((size_t)b2 * D3 + (size_t)h * CHD) * NN;
    const uint16_t* kb = ksrc + ((size_t)b2 * D3 + DIMC + (size_t)h * CHD) * NN;
    const int n0 = ck * 2048;
    const int tc = t >> 4, td = t & 15;
    float acc[3][3] = {};
    for (int sub = 0; sub < 16; ++sub) {
        __syncthreads();
        for (int i = t; i < CHD * 16; i += 256) {
            int r = i >> 4, f = i & 15;
            *reinterpret_cast<uint4*>(&qs[r][f * 8]) =
                *reinterpret_cast<const uint4*>(qb + (size_t)r * NN + n0 + sub * 128 + f * 8);
            *reinterpret_cast<uint4*>(&ks[r][f * 8]) =
                *reinterpret_cast<const uint4*>(kb + (size_t)r * NN + n0 + sub * 128 + f * 8);
        }
        __syncthreads();
#pragma unroll 8
        for (int n2 = 0; n2 < 64; ++n2) {
            const int n = n2 * 2;
            float2 qv[3], kv[3];
#pragma unroll
            for (int i = 0; i < 3; ++i)
                qv[i] = upk2(*reinterpret_cast<const uint32_t*>(&qs[tc + 16 * i][n]));
#pragma unroll
            for (int j = 0; j < 3; ++j)
                kv[j] = upk2(*reinterpret_cast<const uint32_t*>(&ks[td + 16 * j][n]));
#pragma unroll
            for (int i = 0; i < 3; ++i)
#pragma unroll
                for (int j = 0; j < 3; ++j)
                    acc[i][j] += qv[i].x * kv[j].x + qv[i].y * kv[j].y;
        }
    }
    float* pd = partial + ((size_t)pid * 8 + ck) * 2304;
#pragma unroll
    for (int i = 0; i < 3; ++i)
#pragma unroll
        for (int j = 0; j < 3; ++j)
            pd[(tc + 16 * i) * 48 + td + 16 * j] = acc[i][j];
}

// ---------- reduce chunks + scale + softmax ----------
__global__ __launch_bounds__(64) void k_softmax(
    const float* __restrict__ partial, const float* __restrict__ norms,
    const float* __restrict__ ms_temp, const float* __restrict__ sar_temp,
    float* __restrict__ A)
{
    const int lane = threadIdx.x;
    const int bi = blockIdx.x;
    const int c = bi % 48;
    const int pid = bi / 48;
    const int h = pid & 3, b = (pid >> 2) & 3, type = pid >> 4;
    float s;
    if (lane < 48) {
        float accv = 0.f;
        const float* pp = partial + (size_t)pid * 8 * 2304 + c * 48 + lane;
#pragma unroll
        for (int ck = 0; ck < 8; ++ck) accv += pp[(size_t)ck * 2304];
        const int qset = (type == 0) ? 0 : 2;
        const int kset = (type == 1) ? 3 : 1;
        const float tval = (type == 1) ? sar_temp[h] : ms_temp[h];
        const float qsc = norms[qset * 768 + b * DIMC + h * CHD + c];
        const float ksc = norms[kset * 768 + b * DIMC + h * CHD + lane];
        s = accv * qsc * ksc * tval;
    } else {
        s = -3.0e38f;
    }
    float m = s;
#pragma unroll
    for (int o = 32; o > 0; o >>= 1) m = fmaxf(m, __shfl_xor(m, o));
    float e = (lane < 48) ? __expf(s - m) : 0.f;
    float sum = e;
#pragma unroll
    for (int o = 32; o > 0; o >>= 1) sum += __shfl_xor(sum, o);
    if (lane < 48) A[(size_t)pid * 2304 + c * 48 + lane] = e / sum;
}

// ---------- MFMA apply: out[c][n] = sum_d A[c][d] V[d][n] ----------
__global__ __launch_bounds__(256) void k_apply_mfma(
    const float* __restrict__ A, const uint16_t* __restrict__ qkv_ms,
    const uint16_t* __restrict__ qkv_sar, uint16_t* __restrict__ attn)
{
    __shared__ uint16_t vs[256][40];
    __shared__ uint16_t as[48][40];
    const int t = threadIdx.x;
    const int nb = blockIdx.x & 63;
    const int pid = blockIdx.x >> 6;
    const int h = pid & 3, b = (pid >> 2) & 3, type = pid >> 4;
    const int n0 = nb * 256;
    const uint16_t* vsrc = (type == 0) ? qkv_ms : qkv_sar;
    const uint16_t* vb = vsrc + ((size_t)b * D3 + 2 * DIMC + (size_t)h * CHD) * NN;
    const float* Ap = A + (size_t)pid * 2304;

    const int lane = t & 63, wvid = t >> 6;
    const int lm = lane & 15, g = lane >> 4;

    f32x4 acc[3][4];
#pragma unroll
    for (int i = 0; i < 3; ++i)
#pragma unroll
        for (int j = 0; j < 4; ++j) acc[i][j] = (f32x4){0.f, 0.f, 0.f, 0.f};

    const int swu_dummy = 0; (void)swu_dummy;
    for (int k0 = 0; k0 < 64; k0 += 32) {
        __syncthreads();
#pragma unroll
        for (int kh = 0; kh < 2; ++kh) {
            uint16_t vals[16];
#pragma unroll
            for (int j = 0; j < 16; ++j) {
                const int d = k0 + kh * 16 + j;
                vals[j] = (d < CHD) ? vb[(size_t)d * NN + n0 + t] : (uint16_t)0;
            }
            const int u0 = (2 * kh) ^ ((t >> 3) & 3);
            const int u1 = (2 * kh + 1) ^ ((t >> 3) & 3);
            *(uint4*)&vs[t][u0 * 8] = pack8(&vals[0]);
            *(uint4*)&vs[t][u1 * 8] = pack8(&vals[8]);
        }
        if (t < 192) {
            const int c = t >> 2, dq = t & 3;
            uint16_t av[8];
#pragma unroll
            for (int i = 0; i < 8; ++i) {
                const int d = k0 + dq * 8 + i;
                av[i] = (d < CHD) ? f2bf(Ap[c * CHD + d]) : (uint16_t)0;
            }
            const int u = dq ^ ((c >> 3) & 3);
            *(uint4*)&as[c][u * 8] = pack8(av);
        }
        __syncthreads();
        FragU afr[3], bfr[4];
#pragma unroll
        for (int mi = 0; mi < 3; ++mi) {
            const int row = mi * 16 + lm;
            afr[mi].u4 = *(const uint4*)&as[row][(g ^ ((row >> 3) & 3)) * 8];
        }
#pragma unroll
        for (int nj = 0; nj < 4; ++nj) {
            const int row = wvid * 64 + nj * 16 + lm;
            bfr[nj].u4 = *(const uint4*)&vs[row][(g ^ ((row >> 3) & 3)) * 8];
        }
#pragma unroll
        for (int mi = 0; mi < 3; ++mi)
#pragma unroll
            for (int nj = 0; nj < 4; ++nj)
                acc[mi][nj] = __builtin_amdgcn_mfma_f32_16x16x32_bf16(
                    afr[mi].s8, bfr[nj].s8, acc[mi][nj], 0, 0, 0);
    }

    uint16_t* ob = attn + (size_t)type * BB * DIMC * NN +
                   ((size_t)b * DIMC + (size_t)h * CHD) * NN;
#pragma unroll
    for (int mi = 0; mi < 3; ++mi) {
        const int rbase = mi * 16 + g * 4;
#pragma unroll
        for (int nj = 0; nj < 4; ++nj) {
            const int gcol = n0 + wvid * 64 + nj * 16 + lm;
#pragma unroll
            for (int r = 0; r < 4; ++r)
                ob[(size_t)(rbase + r) * NN + gcol] = f2bf(acc[mi][nj][r]);
        }
    }
}

extern "C" void kernel_launch(void* const* d_in, const int* in_sizes, int n_in,
                              void* d_out, int out_size, void* d_ws, size_t ws_size,
                              hipStream_t stream)
{
    const float* sar        = (const float*)d_in[0];
    const float* ms         = (const float*)d_in[1];
    const float* ms_qkv_w   = (const float*)d_in[2];
    const float* ms_qkv_b   = (const float*)d_in[3];
    const float* ms_dw_w    = (const float*)d_in[4];
    const float* ms_dw_b    = (const float*)d_in[5];
    const float* ms_temp    = (const float*)d_in[6];
    const float* sar_qkv_w  = (const float*)d_in[7];
    const float* sar_qkv_b  = (const float*)d_in[8];
    const float* sar_dw_w   = (const float*)d_in[9];
    const float* sar_dw_b   = (const float*)d_in[10];
    const float* sar_temp   = (const float*)d_in[11];
    const float* ms_proj_w  = (const float*)d_in[12];
    const float* ms_proj_b  = (const float*)d_in[13];
    const float* sar_proj_w = (const float*)d_in[14];
    const float* sar_proj_b = (const float*)d_in[15];

    char* ws = (char*)d_ws;
    // ws layout (bytes):
    //   [0,          75497472)  tmp bf16 (conv1x1 out) -> reused for attn outs
    //   [75497472,  150994944)  qkv_ms bf16
    //   [150994944, 226492416)  qkv_sar bf16
    //   [226492416, 226504704)  norm scales f32
    //   [226504704, 230043648)  partial scores f32
    //   [230043648, 230486016)  softmaxed A f32
    //   [230486016, 231149568)  bf16 weights
    uint16_t* tmp     = (uint16_t*)(ws);
    uint16_t* qkv_ms  = (uint16_t*)(ws + 75497472ull);
    uint16_t* qkv_sar = (uint16_t*)(ws + 150994944ull);
    float* norms      = (float*)(ws + 226492416ull);
    float* partial    = (float*)(ws + 226504704ull);
    float* Amat       = (float*)(ws + 230043648ull);
    uint16_t* wq_ms   = (uint16_t*)(ws + 230486016ull);
    uint16_t* wq_sar  = (uint16_t*)(ws + 230707200ull);
    uint16_t* wp1_ms  = (uint16_t*)(ws + 230928384ull);
    uint16_t* wp2_ms  = (uint16_t*)(ws + 231002112ull);
    uint16_t* wp_sar  = (uint16_t*)(ws + 231075840ull);
    uint16_t* attn    = tmp;

    float* out_sar = (float*)d_out;
    float* out_ms  = out_sar + (size_t)BB * DIMC * NN;

    dim3 b256(256);
    k_prep<<<dim3(1152), b256, 0, stream>>>(ms_qkv_w, sar_qkv_w, ms_proj_w, sar_proj_w,
                                            wq_ms, wq_sar, wp1_ms, wp2_ms, wp_sar);
    k_conv_mfma<<<dim3(128 * BB), b256, 0, stream>>>(ms, wq_ms, ms_qkv_b, tmp);
    k_dwconv2<<<dim3(1, 8, BB * D3), b256, 0, stream>>>(tmp, ms_dw_w, ms_dw_b, qkv_ms);
    k_conv_mfma<<<dim3(128 * BB), b256, 0, stream>>>(sar, wq_sar, sar_qkv_b, tmp);
    k_dwconv2<<<dim3(1, 8, BB * D3), b256, 0, stream>>>(tmp, sar_dw_w, sar_dw_b, qkv_sar);

    k_norms<<<dim3(4 * BB * DIMC), b256, 0, stream>>>(qkv_ms, qkv_sar, norms);
    k_scores<<<dim3(48 * 8), b256, 0, stream>>>(qkv_ms, qkv_sar, partial);
    k_softmax<<<dim3(48 * 48), dim3(64), 0, stream>>>(partial, norms, ms_temp, sar_temp, Amat);
    k_apply_mfma<<<dim3(48 * 64), b256, 0, stream>>>(Amat, qkv_ms, qkv_sar, attn);

    uint16_t* ms_self  = attn;
    uint16_t* sar_self = attn + (size_t)BB * DIMC * NN;
    uint16_t* crossb   = attn + 2ull * BB * DIMC * NN;
    k_proj_mfma<1><<<dim3(128 * BB), b256, 0, stream>>>(
        sar_self, nullptr, wp_sar, nullptr, sar_proj_b, sar, out_sar);
    k_proj_mfma<2><<<dim3(128 * BB), b256, 0, stream>>>(
        ms_self, crossb, wp1_ms, wp2_ms, ms_proj_b, ms, out_ms);
}

// Round 4
// 311.713 us; speedup vs baseline: 5.0370x; 1.3397x over previous
//
#include <hip/hip_runtime.h>
#include <hip/hip_bf16.h>
#include <cstdint>

#define DIMC 192
#define BB 4
#define NN 16384
#define D3 576
#define CHD 48
#define WWID 128
#define HHGT 128

typedef short short8 __attribute__((ext_vector_type(8)));
typedef float f32x4 __attribute__((ext_vector_type(4)));

union FragU { uint4 u4; short8 s8; };

// ---------- bf16 helpers ----------
__device__ __forceinline__ float bf2f(uint16_t v) {
    return __uint_as_float(((uint32_t)v) << 16);
}
__device__ __forceinline__ float2 upk2(uint32_t u) {
    float2 r;
    r.x = __uint_as_float(u << 16);
    r.y = __uint_as_float(u & 0xffff0000u);
    return r;
}
__device__ __forceinline__ uint16_t f2bf(float f) {
    uint32_t x = __float_as_uint(f);
    return (uint16_t)((x + 0x7fffu + ((x >> 16) & 1u)) >> 16);
}
__device__ __forceinline__ uint4 pack8(const uint16_t* v) {
    uint4 u;
    u.x = (uint32_t)v[0] | ((uint32_t)v[1] << 16);
    u.y = (uint32_t)v[2] | ((uint32_t)v[3] << 16);
    u.z = (uint32_t)v[4] | ((uint32_t)v[5] << 16);
    u.w = (uint32_t)v[6] | ((uint32_t)v[7] << 16);
    return u;
}

// ---------- K0: weights fp32 -> bf16 (+ folded proj_ms weights) ----------
// wp1_ms = Wa+Wb (applies to ms_self), wp2_ms = Wb (applies to cross):
// W @ concat(self, cross+self) == (Wa+Wb)@self + Wb@cross
__global__ __launch_bounds__(256) void k_prep(
    const float* __restrict__ w0, const float* __restrict__ w1,
    const float* __restrict__ w2, const float* __restrict__ w3,
    uint16_t* __restrict__ o0, uint16_t* __restrict__ o1,
    uint16_t* __restrict__ o2a, uint16_t* __restrict__ o2b,
    uint16_t* __restrict__ o3)
{
    int i = blockIdx.x * 256 + threadIdx.x;
    if (i < 110592) { o0[i] = f2bf(w0[i]); return; }
    i -= 110592;
    if (i < 110592) { o1[i] = f2bf(w1[i]); return; }
    i -= 110592;
    if (i < 36864) {
        const int o = i / DIMC, c = i % DIMC;
        o2a[i] = f2bf(w2[o * 384 + c] + w2[o * 384 + DIMC + c]);
        o2b[i] = f2bf(w2[o * 384 + DIMC + c]);
        return;
    }
    i -= 36864;
    if (i < 36864) o3[i] = f2bf(w3[i]);
}

// ---------- qkv conv1x1 MFMA: out[576][NN] = W[576][192] @ X[192][NN], bf16 out ----------
__global__ __launch_bounds__(256, 2) void k_conv_mfma(
    const float* __restrict__ x, const uint16_t* __restrict__ wbf,
    const float* __restrict__ bias, uint16_t* __restrict__ out)
{
    __shared__ uint16_t xs[128][200];   // [n][k], 400B row stride -> 2-way max
    __shared__ uint16_t wst[64][200];   // [m][k]
    const int t = threadIdx.x;
    const int nb = blockIdx.x & 127;
    const int b = blockIdx.x >> 7;
    const int n0 = nb * 128;

    const int lane = t & 63, wvid = t >> 6;
    const int lm = lane & 15, g = lane >> 4;
    const int wm = wvid >> 1, wn = wvid & 1;

    // ---- stage X once: fp32 -> bf16, transposed to [n][k] ----
    {
        const int sn = t & 127, kh = t >> 7;
        const float* xcol = x + ((size_t)b * DIMC + kh * 96) * NN + n0 + sn;
        for (int u = 0; u < 12; ++u) {
            uint16_t vals[8];
#pragma unroll
            for (int j = 0; j < 8; ++j)
                vals[j] = f2bf(xcol[(size_t)(u * 8 + j) * NN]);
            *(uint4*)&xs[sn][(kh * 12 + u) * 8] = pack8(vals);
        }
    }
    // ---- stage W m-block 0 ----
    {
        const int wm_ = t >> 2, wq = t & 3;
        const uint16_t* wrow = wbf + (size_t)wm_ * DIMC;
#pragma unroll
        for (int i = 0; i < 6; ++i) {
            const int unit = i * 4 + wq;
            *(uint4*)&wst[wm_][unit * 8] = *(const uint4*)&wrow[unit * 8];
        }
    }
    __syncthreads();

    // ---- hoist B fragments (reused across all 9 m-blocks) ----
    FragU bfr[6][4];
#pragma unroll
    for (int ks = 0; ks < 6; ++ks)
#pragma unroll
        for (int nj = 0; nj < 4; ++nj) {
            const int row = wn * 64 + nj * 16 + lm;
            bfr[ks][nj].u4 = *(const uint4*)&xs[row][ks * 32 + g * 8];
        }

    for (int mb = 0; mb < 9; ++mb) {
        if (mb) {
            __syncthreads();
            const int wm_ = t >> 2, wq = t & 3;
            const uint16_t* wrow = wbf + (size_t)(mb * 64 + wm_) * DIMC;
#pragma unroll
            for (int i = 0; i < 6; ++i) {
                const int unit = i * 4 + wq;
                *(uint4*)&wst[wm_][unit * 8] = *(const uint4*)&wrow[unit * 8];
            }
            __syncthreads();
        }
        f32x4 acc[2][4];
#pragma unroll
        for (int mi = 0; mi < 2; ++mi)
#pragma unroll
            for (int nj = 0; nj < 4; ++nj) acc[mi][nj] = (f32x4){0.f, 0.f, 0.f, 0.f};
#pragma unroll
        for (int ks = 0; ks < 6; ++ks) {
            FragU afr[2];
#pragma unroll
            for (int mi = 0; mi < 2; ++mi) {
                const int row = wm * 32 + mi * 16 + lm;
                afr[mi].u4 = *(const uint4*)&wst[row][ks * 32 + g * 8];
            }
#pragma unroll
            for (int mi = 0; mi < 2; ++mi)
#pragma unroll
                for (int nj = 0; nj < 4; ++nj)
                    acc[mi][nj] = __builtin_amdgcn_mfma_f32_16x16x32_bf16(
                        afr[mi].s8, bfr[ks][nj].s8, acc[mi][nj], 0, 0, 0);
        }
        // epilogue for this m-block
#pragma unroll
        for (int mi = 0; mi < 2; ++mi) {
            const int rbase = mb * 64 + wm * 32 + mi * 16 + g * 4;
            const float4 bv = *(const float4*)&bias[rbase];
            const float bva[4] = {bv.x, bv.y, bv.z, bv.w};
#pragma unroll
            for (int nj = 0; nj < 4; ++nj) {
                const int gcol = n0 + wn * 64 + nj * 16 + lm;
#pragma unroll
                for (int r = 0; r < 4; ++r)
                    out[((size_t)b * D3 + rbase + r) * NN + gcol] =
                        f2bf(acc[mi][nj][r] + bva[r]);
            }
        }
    }
}

// ---------- proj MFMA: out[192][NN] = sum_ph W_ph[192][192] @ X_ph[192][NN] + resid ----------
template<int PHASES>
__global__ __launch_bounds__(256, 2) void k_proj_mfma(
    const uint16_t* __restrict__ x0, const uint16_t* __restrict__ x1,
    const uint16_t* __restrict__ w0, const uint16_t* __restrict__ w1,
    const float* __restrict__ bias, const float* __restrict__ resid,
    float* __restrict__ out)
{
    __shared__ uint16_t xs[128][200];
    __shared__ uint16_t wst[64][200];
    const int t = threadIdx.x;
    const int nb = blockIdx.x & 127;
    const int b = blockIdx.x >> 7;
    const int n0 = nb * 128;

    const int lane = t & 63, wvid = t >> 6;
    const int lm = lane & 15, g = lane >> 4;
    const int wm = wvid >> 1, wn = wvid & 1;

    f32x4 acc[3][2][4];
#pragma unroll
    for (int mb = 0; mb < 3; ++mb)
#pragma unroll
        for (int mi = 0; mi < 2; ++mi)
#pragma unroll
            for (int nj = 0; nj < 4; ++nj) acc[mb][mi][nj] = (f32x4){0.f, 0.f, 0.f, 0.f};

    for (int ph = 0; ph < PHASES; ++ph) {
        const uint16_t* xsrc = ph ? x1 : x0;
        const uint16_t* wsrc = ph ? w1 : w0;
        if (ph) __syncthreads();
        // stage X (bf16, transpose to [n][k])
        {
            const int sn = t & 127, kh = t >> 7;
            const uint16_t* xcol = xsrc + ((size_t)b * DIMC + kh * 96) * NN + n0 + sn;
            for (int u = 0; u < 12; ++u) {
                uint16_t vals[8];
#pragma unroll
                for (int j = 0; j < 8; ++j)
                    vals[j] = xcol[(size_t)(u * 8 + j) * NN];
                *(uint4*)&xs[sn][(kh * 12 + u) * 8] = pack8(vals);
            }
        }
        // stage W m-block 0
        {
            const int wm_ = t >> 2, wq = t & 3;
            const uint16_t* wrow = wsrc + (size_t)wm_ * DIMC;
#pragma unroll
            for (int i = 0; i < 6; ++i) {
                const int unit = i * 4 + wq;
                *(uint4*)&wst[wm_][unit * 8] = *(const uint4*)&wrow[unit * 8];
            }
        }
        __syncthreads();
        FragU bfr[6][4];
#pragma unroll
        for (int ks = 0; ks < 6; ++ks)
#pragma unroll
            for (int nj = 0; nj < 4; ++nj) {
                const int row = wn * 64 + nj * 16 + lm;
                bfr[ks][nj].u4 = *(const uint4*)&xs[row][ks * 32 + g * 8];
            }
        for (int mb = 0; mb < 3; ++mb) {
            if (mb) {
                __syncthreads();
                const int wm_ = t >> 2, wq = t & 3;
                const uint16_t* wrow = wsrc + (size_t)(mb * 64 + wm_) * DIMC;
#pragma unroll
                for (int i = 0; i < 6; ++i) {
                    const int unit = i * 4 + wq;
                    *(uint4*)&wst[wm_][unit * 8] = *(const uint4*)&wrow[unit * 8];
                }
                __syncthreads();
            }
#pragma unroll
            for (int ks = 0; ks < 6; ++ks) {
                FragU afr[2];
#pragma unroll
                for (int mi = 0; mi < 2; ++mi) {
                    const int row = wm * 32 + mi * 16 + lm;
                    afr[mi].u4 = *(const uint4*)&wst[row][ks * 32 + g * 8];
                }
#pragma unroll
                for (int mi = 0; mi < 2; ++mi)
#pragma unroll
                    for (int nj = 0; nj < 4; ++nj)
                        acc[mb][mi][nj] = __builtin_amdgcn_mfma_f32_16x16x32_bf16(
                            afr[mi].s8, bfr[ks][nj].s8, acc[mb][mi][nj], 0, 0, 0);
            }
        }
    }
    // epilogue: bias + residual, fp32 out
#pragma unroll
    for (int mb = 0; mb < 3; ++mb)
#pragma unroll
        for (int mi = 0; mi < 2; ++mi) {
            const int rbase = mb * 64 + wm * 32 + mi * 16 + g * 4;
            const float4 bv = *(const float4*)&bias[rbase];
            const float bva[4] = {bv.x, bv.y, bv.z, bv.w};
#pragma unroll
            for (int nj = 0; nj < 4; ++nj) {
                const int gcol = n0 + wn * 64 + nj * 16 + lm;
#pragma unroll
                for (int r = 0; r < 4; ++r) {
                    const size_t idx = ((size_t)b * DIMC + rbase + r) * NN + gcol;
                    out[idx] = resid[idx] + acc[mb][mi][nj][r] + bva[r];
                }
            }
        }
}

// ---------- depthwise 3x3 + bias, 8 px/thread ----------
__global__ __launch_bounds__(256) void k_dwconv2(
    const uint16_t* __restrict__ in, const float* __restrict__ w9,
    const float* __restrict__ bias, uint16_t* __restrict__ out)
{
    const int t = threadIdx.x;
    const int bc = blockIdx.z;
    const int ch = bc % D3;
    const int xg = t & 15, yl = t >> 4;
    const int x0 = xg * 8;
    const int y = blockIdx.y * 16 + yl;
    const uint16_t* p = in + (size_t)bc * NN;
    float wv[9];
#pragma unroll
    for (int k = 0; k < 9; ++k) wv[k] = w9[ch * 9 + k];
    float r[3][10];
#pragma unroll
    for (int dy = 0; dy < 3; ++dy) {
        const int yy = y + dy - 1;
        if (yy < 0 || yy >= HHGT) {
#pragma unroll
            for (int j = 0; j < 10; ++j) r[dy][j] = 0.f;
        } else {
            const uint16_t* row = p + yy * WWID;
            uint4 u = *(const uint4*)(row + x0);
            const uint16_t* pv = (const uint16_t*)&u;
#pragma unroll
            for (int j = 0; j < 8; ++j) r[dy][j + 1] = bf2f(pv[j]);
            r[dy][0] = (x0 > 0) ? bf2f(row[x0 - 1]) : 0.f;
            r[dy][9] = (x0 + 8 < WWID) ? bf2f(row[x0 + 8]) : 0.f;
        }
    }
    const float base = bias[ch];
    uint16_t ov[8];
#pragma unroll
    for (int j = 0; j < 8; ++j) {
        float a = base;
#pragma unroll
        for (int dy = 0; dy < 3; ++dy)
#pragma unroll
            for (int dx = 0; dx < 3; ++dx)
                a = fmaf(r[dy][j + dx], wv[dy * 3 + dx], a);
        ov[j] = f2bf(a);
    }
    *(uint4*)(out + (size_t)bc * NN + y * WWID + x0) = pack8(ov);
}

// ---------- MFMA scores + fused norm partials ----------
// grid = 16 pid (b*4+h) x 16 chunks of 1024. Waves 0-2: one Gram each
// (0=ms_self, 1=sar_self, 2=cross) via direct-global MFMA fragments.
// Wave 3: sumsq partials of the 4x48 q/k rows (replaces k_norms).
__global__ __launch_bounds__(256) void k_scores_mfma(
    const uint16_t* __restrict__ qkv_ms, const uint16_t* __restrict__ qkv_sar,
    float* __restrict__ partial, float* __restrict__ sumsq)
{
    const int t = threadIdx.x;
    const int bid = blockIdx.x;
    const int ck = bid & 15;
    const int pid = bid >> 4;          // b*4 + h
    const int h = pid & 3, b = pid >> 2;
    const int n0 = ck * 1024;
    const int lane = t & 63, w = t >> 6;

    const uint16_t* qm  = qkv_ms  + ((size_t)b * D3 + h * CHD) * NN;
    const uint16_t* km  = qkv_ms  + ((size_t)b * D3 + DIMC + h * CHD) * NN;
    const uint16_t* qsr = qkv_sar + ((size_t)b * D3 + h * CHD) * NN;
    const uint16_t* ksr = qkv_sar + ((size_t)b * D3 + DIMC + h * CHD) * NN;

    if (w < 3) {
        const uint16_t* qb = (w == 0) ? qm : qsr;
        const uint16_t* kb = (w == 1) ? ksr : km;
        const int lm = lane & 15, g = lane >> 4;
        f32x4 acc[3][3];
#pragma unroll
        for (int i = 0; i < 3; ++i)
#pragma unroll
            for (int j = 0; j < 3; ++j) acc[i][j] = (f32x4){0.f, 0.f, 0.f, 0.f};
        for (int kk = 0; kk < 32; ++kk) {
            const int nb2 = n0 + kk * 32 + g * 8;
            FragU qf[3], kf[3];
#pragma unroll
            for (int i = 0; i < 3; ++i)
                qf[i].u4 = *(const uint4*)&qb[(size_t)(i * 16 + lm) * NN + nb2];
#pragma unroll
            for (int j = 0; j < 3; ++j)
                kf[j].u4 = *(const uint4*)&kb[(size_t)(j * 16 + lm) * NN + nb2];
#pragma unroll
            for (int i = 0; i < 3; ++i)
#pragma unroll
                for (int j = 0; j < 3; ++j)
                    acc[i][j] = __builtin_amdgcn_mfma_f32_16x16x32_bf16(
                        qf[i].s8, kf[j].s8, acc[i][j], 0, 0, 0);
        }
        float* pd = partial + (((size_t)pid * 3 + w) * 16 + ck) * 2304;
        const int g4 = g * 4;
#pragma unroll
        for (int i = 0; i < 3; ++i)
#pragma unroll
            for (int j = 0; j < 3; ++j)
#pragma unroll
                for (int r = 0; r < 4; ++r)
                    pd[(i * 16 + g4 + r) * 48 + j * 16 + lm] = acc[i][j][r];
    } else {
        // sumsq of 192 rows (sets: 0=q_ms 1=k_ms 2=q_sar 3=k_sar) over chunk
#pragma unroll
        for (int rep = 0; rep < 3; ++rep) {
            const int rid = rep * 64 + lane;
            const int s = rid / CHD, c = rid % CHD;
            const uint16_t* rowp =
                (s == 0) ? qm  + (size_t)c * NN :
                (s == 1) ? km  + (size_t)c * NN :
                (s == 2) ? qsr + (size_t)c * NN :
                           ksr + (size_t)c * NN;
            float sum = 0.f;
            for (int u = 0; u < 128; ++u) {
                uint4 v = *(const uint4*)&rowp[n0 + u * 8];
                uint32_t uu[4] = {v.x, v.y, v.z, v.w};
#pragma unroll
                for (int q = 0; q < 4; ++q) {
                    float2 f = upk2(uu[q]);
                    sum = fmaf(f.x, f.x, fmaf(f.y, f.y, sum));
                }
            }
            sumsq[(((size_t)pid * 16 + ck) * 4 + s) * CHD + c] = sum;
        }
    }
}

// ---------- reduce chunks + norm scale + softmax ----------
__global__ __launch_bounds__(64) void k_softmax(
    const float* __restrict__ partial, const float* __restrict__ sumsq,
    const float* __restrict__ ms_temp, const float* __restrict__ sar_temp,
    float* __restrict__ A)
{
    const int lane = threadIdx.x;
    const int bi = blockIdx.x;
    const int c = bi % 48;
    const int pid = bi / 48;               // type*16 + b*4 + h
    const int h = pid & 3, b = (pid >> 2) & 3, type = pid >> 4;
    const int pid16 = b * 4 + h;
    float s;
    if (lane < 48) {
        float accv = 0.f;
        const float* pp = partial + ((size_t)pid16 * 3 + type) * 16 * 2304 + c * 48 + lane;
#pragma unroll
        for (int ck = 0; ck < 16; ++ck) accv += pp[(size_t)ck * 2304];
        const int qset = (type == 0) ? 0 : 2;
        const int kset = (type == 1) ? 3 : 1;
        float qsum = 0.f, ksum = 0.f;
        const float* sq = sumsq + (size_t)pid16 * 16 * 4 * CHD;
#pragma unroll
        for (int ck = 0; ck < 16; ++ck) {
            qsum += sq[ck * 4 * CHD + qset * CHD + c];
            ksum += sq[ck * 4 * CHD + kset * CHD + lane];
        }
        const float tval = (type == 1) ? sar_temp[h] : ms_temp[h];
        const float qsc = 1.0f / fmaxf(sqrtf(qsum), 1e-12f);
        const float ksc = 1.0f / fmaxf(sqrtf(ksum), 1e-12f);
        s = accv * qsc * ksc * tval;
    } else {
        s = -3.0e38f;
    }
    float m = s;
#pragma unroll
    for (int o = 32; o > 0; o >>= 1) m = fmaxf(m, __shfl_xor(m, o));
    float e = (lane < 48) ? __expf(s - m) : 0.f;
    float sum = e;
#pragma unroll
    for (int o = 32; o > 0; o >>= 1) sum += __shfl_xor(sum, o);
    if (lane < 48) A[(size_t)pid * 2304 + c * 48 + lane] = e / sum;
}

// ---------- MFMA apply: out[c][n] = sum_d A[c][d] V[d][n] ----------
__global__ __launch_bounds__(256) void k_apply_mfma(
    const float* __restrict__ A, const uint16_t* __restrict__ qkv_ms,
    const uint16_t* __restrict__ qkv_sar, uint16_t* __restrict__ attn)
{
    __shared__ uint16_t vs[256][40];
    __shared__ uint16_t as[48][40];
    const int t = threadIdx.x;
    const int nb = blockIdx.x & 63;
    const int pid = blockIdx.x >> 6;
    const int h = pid & 3, b = (pid >> 2) & 3, type = pid >> 4;
    const int n0 = nb * 256;
    const uint16_t* vsrc = (type == 0) ? qkv_ms : qkv_sar;
    const uint16_t* vb = vsrc + ((size_t)b * D3 + 2 * DIMC + (size_t)h * CHD) * NN;
    const float* Ap = A + (size_t)pid * 2304;

    const int lane = t & 63, wvid = t >> 6;
    const int lm = lane & 15, g = lane >> 4;

    f32x4 acc[3][4];
#pragma unroll
    for (int i = 0; i < 3; ++i)
#pragma unroll
        for (int j = 0; j < 4; ++j) acc[i][j] = (f32x4){0.f, 0.f, 0.f, 0.f};

    for (int k0 = 0; k0 < 64; k0 += 32) {
        __syncthreads();
#pragma unroll
        for (int kh = 0; kh < 2; ++kh) {
            uint16_t vals[16];
#pragma unroll
            for (int j = 0; j < 16; ++j) {
                const int d = k0 + kh * 16 + j;
                vals[j] = (d < CHD) ? vb[(size_t)d * NN + n0 + t] : (uint16_t)0;
            }
            const int u0 = (2 * kh) ^ ((t >> 3) & 3);
            const int u1 = (2 * kh + 1) ^ ((t >> 3) & 3);
            *(uint4*)&vs[t][u0 * 8] = pack8(&vals[0]);
            *(uint4*)&vs[t][u1 * 8] = pack8(&vals[8]);
        }
        if (t < 192) {
            const int c = t >> 2, dq = t & 3;
            uint16_t av[8];
#pragma unroll
            for (int i = 0; i < 8; ++i) {
                const int d = k0 + dq * 8 + i;
                av[i] = (d < CHD) ? f2bf(Ap[c * CHD + d]) : (uint16_t)0;
            }
            const int u = dq ^ ((c >> 3) & 3);
            *(uint4*)&as[c][u * 8] = pack8(av);
        }
        __syncthreads();
        FragU afr[3], bfr[4];
#pragma unroll
        for (int mi = 0; mi < 3; ++mi) {
            const int row = mi * 16 + lm;
            afr[mi].u4 = *(const uint4*)&as[row][(g ^ ((row >> 3) & 3)) * 8];
        }
#pragma unroll
        for (int nj = 0; nj < 4; ++nj) {
            const int row = wvid * 64 + nj * 16 + lm;
            bfr[nj].u4 = *(const uint4*)&vs[row][(g ^ ((row >> 3) & 3)) * 8];
        }
#pragma unroll
        for (int mi = 0; mi < 3; ++mi)
#pragma unroll
            for (int nj = 0; nj < 4; ++nj)
                acc[mi][nj] = __builtin_amdgcn_mfma_f32_16x16x32_bf16(
                    afr[mi].s8, bfr[nj].s8, acc[mi][nj], 0, 0, 0);
    }

    uint16_t* ob = attn + (size_t)type * BB * DIMC * NN +
                   ((size_t)b * DIMC + (size_t)h * CHD) * NN;
#pragma unroll
    for (int mi = 0; mi < 3; ++mi) {
        const int rbase = mi * 16 + g * 4;
#pragma unroll
        for (int nj = 0; nj < 4; ++nj) {
            const int gcol = n0 + wvid * 64 + nj * 16 + lm;
#pragma unroll
            for (int r = 0; r < 4; ++r)
                ob[(size_t)(rbase + r) * NN + gcol] = f2bf(acc[mi][nj][r]);
        }
    }
}

extern "C" void kernel_launch(void* const* d_in, const int* in_sizes, int n_in,
                              void* d_out, int out_size, void* d_ws, size_t ws_size,
                              hipStream_t stream)
{
    const float* sar        = (const float*)d_in[0];
    const float* ms         = (const float*)d_in[1];
    const float* ms_qkv_w   = (const float*)d_in[2];
    const float* ms_qkv_b   = (const float*)d_in[3];
    const float* ms_dw_w    = (const float*)d_in[4];
    const float* ms_dw_b    = (const float*)d_in[5];
    const float* ms_temp    = (const float*)d_in[6];
    const float* sar_qkv_w  = (const float*)d_in[7];
    const float* sar_qkv_b  = (const float*)d_in[8];
    const float* sar_dw_w   = (const float*)d_in[9];
    const float* sar_dw_b   = (const float*)d_in[10];
    const float* sar_temp   = (const float*)d_in[11];
    const float* ms_proj_w  = (const float*)d_in[12];
    const float* ms_proj_b  = (const float*)d_in[13];
    const float* sar_proj_w = (const float*)d_in[14];
    const float* sar_proj_b = (const float*)d_in[15];

    char* ws = (char*)d_ws;
    // ws layout (bytes):
    //   [0,          75497472)  tmp bf16 (conv1x1 out) -> score partials scratch
    //                           (dead after dwconv; partials dead after softmax)
    //                           -> finally attn outputs (written by apply)
    //   [75497472,  150994944)  qkv_ms bf16
    //   [150994944, 226492416)  qkv_sar bf16
    //   [230043648, 230486016)  softmaxed A f32
    //   [230486016, 231149568)  bf16 weights
    uint16_t* tmp     = (uint16_t*)(ws);
    uint16_t* qkv_ms  = (uint16_t*)(ws + 75497472ull);
    uint16_t* qkv_sar = (uint16_t*)(ws + 150994944ull);
    float* partial    = (float*)(ws);             // 7.08 MB, inside tmp
    float* sumsq      = (float*)(ws + 8388608ull);// 0.79 MB, inside tmp
    float* Amat       = (float*)(ws + 230043648ull);
    uint16_t* wq_ms   = (uint16_t*)(ws + 230486016ull);
    uint16_t* wq_sar  = (uint16_t*)(ws + 230707200ull);
    uint16_t* wp1_ms  = (uint16_t*)(ws + 230928384ull);
    uint16_t* wp2_ms  = (uint16_t*)(ws + 231002112ull);
    uint16_t* wp_sar  = (uint16_t*)(ws + 231075840ull);
    uint16_t* attn    = tmp;

    float* out_sar = (float*)d_out;
    float* out_ms  = out_sar + (size_t)BB * DIMC * NN;

    dim3 b256(256);
    k_prep<<<dim3(1152), b256, 0, stream>>>(ms_qkv_w, sar_qkv_w, ms_proj_w, sar_proj_w,
                                            wq_ms, wq_sar, wp1_ms, wp2_ms, wp_sar);
    k_conv_mfma<<<dim3(128 * BB), b256, 0, stream>>>(ms, wq_ms, ms_qkv_b, tmp);
    k_dwconv2<<<dim3(1, 8, BB * D3), b256, 0, stream>>>(tmp, ms_dw_w, ms_dw_b, qkv_ms);
    k_conv_mfma<<<dim3(128 * BB), b256, 0, stream>>>(sar, wq_sar, sar_qkv_b, tmp);
    k_dwconv2<<<dim3(1, 8, BB * D3), b256, 0, stream>>>(tmp, sar_dw_w, sar_dw_b, qkv_sar);

    k_scores_mfma<<<dim3(256), b256, 0, stream>>>(qkv_ms, qkv_sar, partial, sumsq);
    k_softmax<<<dim3(48 * 48), dim3(64), 0, stream>>>(partial, sumsq, ms_temp, sar_temp, Amat);
    k_apply_mfma<<<dim3(48 * 64), b256, 0, stream>>>(Amat, qkv_ms, qkv_sar, attn);

    uint16_t* ms_self  = attn;
    uint16_t* sar_self = attn + (size_t)BB * DIMC * NN;
    uint16_t* crossb   = attn + 2ull * BB * DIMC * NN;
    k_proj_mfma<1><<<dim3(128 * BB), b256, 0, stream>>>(
        sar_self, nullptr, wp_sar, nullptr, sar_proj_b, sar, out_sar);
    k_proj_mfma<2><<<dim3(128 * BB), b256, 0, stream>>>(
        ms_self, crossb, wp1_ms, wp2_ms, ms_proj_b, ms, out_ms);
}